// Round 10
// baseline (200.399 us; speedup 1.0000x reference)
//
#include <hip/hip_runtime.h>

// Multi-head attention, B=2 S=2048 D=768 H=12 DK=64. I/O fp32, internal bf16 MFMA.
// Round 17: REVERT to R8 baseline (TM=128 QKV + TM=64 out-proj; 199us raw, best
// clock-normalized). R9's TM=64 QKV failed absmax 7.5e-3 with an audit-clean
// source (staging/readout/swizzle all verified by hand) — unexplained; banked
// as "do not retry without per-kernel counters".
// New this round (both zero-indexing-risk):
//  - attn XCD-bh-grouping swizzle: block L -> xcd=L&7 owns bh in {3x,3x+1,3x+2}
//    (1.5MB K/V per XCD L2, was 8x redundant L2 fetch across XCDs). Bijective.
//  - T5 s_setprio(1) around attn MFMA clusters (QK^T and lsum+PV): prio MFMA
//    waves over other resident blocks' staging waves (m191 attn mechanism).
// R16 lesson: fillBufferAligned = constant-work clock probe; normalize walls.
// R15: plain launch_bounds on attn ((256,4) caused 64-VGPR spills). Keep:
// lsum-via-MFMA denominator (bank conflicts 49K->0), TM=64 out-proj, XCD
// swizzle on GEMMs. R13: gatherKV once, streaming. R10: GEMM 2-phase pipeline
// (dbuf LDS + counted vmcnt + raw s_barrier). R9: mask compaction; no mask path
// in attn (zero pads -> p=1, corrected in denominator); Q pre-scaled by
// 0.125*log2(e) -> softmax is raw v_exp_f32.
// Replay-hardening: idx/nk scratch in d_out; no early return before barriers;
// no inline-asm transcendentals. attn LDS strides 72/68 proven conflict-free.

#define H_ 12
#define DK_ 64
#define B_DIM 2
#define SEQ 2048
#define DM 768
#define MROWS 4096
#define PER_IN ((size_t)MROWS * DM)
#define QSCALE 0.18033688011112042f

typedef short bf16x8 __attribute__((ext_vector_type(8)));
typedef short bf16x4 __attribute__((ext_vector_type(4)));
typedef float f32x4 __attribute__((ext_vector_type(4)));
typedef float f32x16 __attribute__((ext_vector_type(16)));

__device__ inline unsigned short f2bf(float f) {
    union { float f; unsigned int i; } x; x.f = f;
    unsigned int r = x.i + 0x7fff + ((x.i >> 16) & 1); // RNE
    return (unsigned short)(r >> 16);
}

__device__ inline unsigned pack2bf(float lo, float hi) {
#if __has_builtin(__builtin_amdgcn_cvt_pk_bf16_f32)
    auto v = __builtin_amdgcn_cvt_pk_bf16_f32(lo, hi);
    return __builtin_bit_cast(unsigned, v);
#else
    return (unsigned)f2bf(lo) | ((unsigned)f2bf(hi) << 16);
#endif
}

__device__ inline float exp2fast(float x) { // 2^x
#if __has_builtin(__builtin_amdgcn_exp2f)
    return __builtin_amdgcn_exp2f(x);
#else
    return exp2f(x);
#endif
}

__device__ inline f32x16 mfma32x8(bf16x4 a, bf16x4 b, f32x16 c) {
#if __has_builtin(__builtin_amdgcn_mfma_f32_32x32x8bf16_1k)
    return __builtin_amdgcn_mfma_f32_32x32x8bf16_1k(a, b, c, 0, 0, 0);
#else
    asm("v_mfma_f32_32x32x8_bf16 %0, %1, %2, %0" : "+v"(c) : "v"(a), "v"(b));
    return c;
#endif
}

// async 16B/lane global->LDS; ldsbase must be wave-uniform (HW adds lane*16B)
__device__ inline void gload_lds16(const unsigned short* g, unsigned short* ldsbase,
                                   int lane) {
#if __has_builtin(__builtin_amdgcn_global_load_lds)
    __builtin_amdgcn_global_load_lds(
        (const __attribute__((address_space(1))) unsigned int*)g,
        (__attribute__((address_space(3))) unsigned int*)ldsbase, 16, 0, 0);
#else
    *(uint4*)(ldsbase + 8 * lane) = *(const uint4*)g;
#endif
}

// -------- prep: fp32->bf16 convert x3  |  4 weight transposes  |  mask scan ---
__global__ __launch_bounds__(256) void prep(
    const float* __restrict__ q, const float* __restrict__ k,
    const float* __restrict__ v,
    unsigned short* __restrict__ qb, unsigned short* __restrict__ kb,
    unsigned short* __restrict__ vb,
    const float* __restrict__ w0, const float* __restrict__ w1,
    const float* __restrict__ w2, const float* __restrict__ w3,
    unsigned short* __restrict__ wtbase,
    const int* __restrict__ mask, int* __restrict__ idx,
    int* __restrict__ nkeys) {
    __shared__ unsigned short t[32][33];
    __shared__ int wsum[4];
    int job = blockIdx.x, tid = threadIdx.x;
    if (job < 9216) { // ---- convert ----
        int buf = job / 3072, x = job % 3072;
        const float* src = buf == 0 ? q : (buf == 1 ? k : v);
        unsigned short* dst = buf == 0 ? qb : (buf == 1 ? kb : vb);
        size_t i = ((size_t)x * 256 + tid) * 4;
        float4 f = *(const float4*)(src + i);
        ushort4 u;
        u.x = f2bf(f.x); u.y = f2bf(f.y); u.z = f2bf(f.z); u.w = f2bf(f.w);
        *(ushort4*)(dst + i) = u;
    } else if (job < 11520) { // ---- weight transpose Wt[n][k] = bf16(W[k][n]) --
        int tb = job - 9216;
        int z = tb / 576, r = tb % 576, by = r / 24, bx = r % 24;
        const float* in = z == 0 ? w0 : (z == 1 ? w1 : (z == 2 ? w2 : w3));
        unsigned short* out = wtbase + (size_t)z * DM * DM;
        int x = tid & 31, y = tid >> 5; // 32 x 8
        int k0 = bx * 32, n0 = by * 32;
#pragma unroll
        for (int i = 0; i < 32; i += 8)
            t[y + i][x] = f2bf(in[(size_t)(k0 + y + i) * DM + n0 + x]);
        __syncthreads();
#pragma unroll
        for (int i = 0; i < 32; i += 8)
            out[(size_t)(n0 + y + i) * DM + k0 + x] = t[x][y + i];
    } else { // ---- mask scan: compact indices of unmasked keys ----
        int b = job - 11520;
        int lane = tid & 63, wave = tid >> 6;
        const int* mp = mask + (size_t)b * SEQ + tid * 8;
        int4 a = *(const int4*)mp;
        int4 c = *(const int4*)(mp + 4);
        int m[8] = {a.x, a.y, a.z, a.w, c.x, c.y, c.z, c.w};
        int pre[8], s = 0;
#pragma unroll
        for (int e = 0; e < 8; e++) { pre[e] = s; s += (m[e] != 0); }
        int incl = s;
#pragma unroll
        for (int off = 1; off < 64; off <<= 1) {
            int vv = __shfl_up(incl, off);
            if (lane >= off) incl += vv;
        }
        int lexcl = incl - s;
        if (lane == 63) wsum[wave] = incl;
        __syncthreads();
        int base = lexcl;
        for (int w = 0; w < wave; w++) base += wsum[w];
#pragma unroll
        for (int e = 0; e < 8; e++)
            if (m[e]) idx[b * SEQ + base + pre[e]] = tid * 8 + e;
        if (tid == 0) nkeys[b] = wsum[0] + wsum[1] + wsum[2] + wsum[3];
    }
}

// -------- gather compacted K rows + transposed V columns, zero-padded --------
__global__ __launch_bounds__(256) void gatherKV(const unsigned short* __restrict__ Kh,
                                                const unsigned short* __restrict__ Vn,
                                                const int* __restrict__ idx,
                                                const int* __restrict__ nkeys,
                                                unsigned short* __restrict__ Kc,
                                                unsigned short* __restrict__ Vtc) {
    __shared__ unsigned short Tl[64][72];
    int tid = threadIdx.x;
    int j0 = blockIdx.x * 64, bh = blockIdx.y, b = bh / H_;
    int n = nkeys[b];
    int row = tid >> 2, cb = (tid & 3) * 16;
    int j = j0 + row;
    int src = j < n ? idx[b * SEQ + j] : -1;
    unsigned short v[16];
    unsigned short* ok = Kc + ((size_t)bh * SEQ + j) * DK_ + cb;
    if (src >= 0) {
        const unsigned short* gv = Vn + ((size_t)bh * SEQ + src) * DK_ + cb;
        *(uint4*)&v[0] = *(const uint4*)gv;
        *(uint4*)&v[8] = *(const uint4*)(gv + 8);
        const unsigned short* gk = Kh + ((size_t)bh * SEQ + src) * DK_ + cb;
        uint4 k0 = *(const uint4*)gk;
        uint4 k1 = *(const uint4*)(gk + 8);
        *(uint4*)ok = k0;
        *(uint4*)(ok + 8) = k1;
    } else { // pad/tail: zero K row and V row -> s=0, p=1 (corrected), p*V=0
        uint4 z = {0u, 0u, 0u, 0u};
        *(uint4*)&v[0] = z;
        *(uint4*)&v[8] = z;
        *(uint4*)ok = z;
        *(uint4*)(ok + 8) = z;
    }
#pragma unroll
    for (int e = 0; e < 16; e++)
        Tl[cb + e][row] = v[e];
    __syncthreads();
    uint4 o0 = *(const uint4*)&Tl[row][cb];
    uint4 o1 = *(const uint4*)&Tl[row][cb + 8];
    unsigned short* out = Vtc + ((size_t)bh * DK_ + row) * SEQ + j0 + cb;
    *(uint4*)out = o0;
    *(uint4*)(out + 8) = o1;
}

// ------------- GEMM: C[m][n] = A[m][:] . Wt[n][:] + bias[n], TM x 128 --------
// 2-phase pipeline: LDS double-buffer; stage(t+1) issued BEFORE waiting on
// tile t (counted vmcnt = next tile's loads in flight); raw s_barrier.
// TM=128: 8 loads/wave/stage, 64KB, 2 blk/CU. TM=64: 6 loads, 48KB, 3 blk/CU.
template <int QKV, int TM>
__global__ __launch_bounds__(256) void gemm128(
    const unsigned short* __restrict__ A0, const unsigned short* __restrict__ A1,
    const unsigned short* __restrict__ A2, const unsigned short* __restrict__ Wt,
    const float* __restrict__ bias0, const float* __restrict__ bias1,
    const float* __restrict__ bias2,
    void* __restrict__ O0, void* __restrict__ O1, void* __restrict__ O2) {
    __shared__ unsigned short S[2][TM + 128][64]; // rows [0,TM)=A, [TM,TM+128)=B
    const int K = DM;
    const int NT = K / 64; // 12
    constexpr int NI = TM / 32; // acc row-frags per wave
    constexpr int AC = TM / 32; // A-stage instrs per wave
    int tid = threadIdx.x;
    int wave = tid >> 6, lane = tid & 63, quad = lane >> 4, l15 = lane & 15;
    int wr = wave >> 1, wc = wave & 1;

    // XCD-aware bijective swizzle (nwg % 8 == 0 for both grids)
    int nwg = gridDim.x * gridDim.y;
    int lin = blockIdx.y * gridDim.x + blockIdx.x;
    int swz = (lin & 7) * (nwg >> 3) + (lin >> 3);
    int bx = swz % gridDim.x, by = swz / gridDim.x;
    int m0 = bx * TM, n0 = by * 128;
    int lrow = lane >> 3, lcol = (lane & 7) * 8;

    int mi = 0, nb0 = n0;
    const unsigned short* A = A0;
    const float* bias = bias0;
    void* O = O0;
    if constexpr (QKV) {
        mi = n0 >= 1536 ? 2 : (n0 >= 768 ? 1 : 0);
        nb0 = n0 - mi * 768;
        A = mi == 0 ? A0 : (mi == 1 ? A1 : A2);
        bias = mi == 0 ? bias0 : (mi == 1 ? bias1 : bias2);
        O = mi == 0 ? O0 : (mi == 1 ? O1 : O2);
    }

    f32x4 acc[NI][4];
#pragma unroll
    for (int i = 0; i < NI; i++)
#pragma unroll
        for (int j = 0; j < 4; j++)
#pragma unroll
            for (int r = 0; r < 4; r++) acc[i][j][r] = 0.f;

    const unsigned short* gA = A + (size_t)(m0 + (TM / 4) * wave + lrow) * K + lcol;
    const unsigned short* gB = Wt + (size_t)(n0 + 32 * wave + lrow) * K + lcol;

    // prologue: stage tile 0 into buf 0
#pragma unroll
    for (int c = 0; c < AC; c++)
        gload_lds16(gA + (size_t)8 * c * K, &S[0][(TM / 4) * wave + 8 * c][0], lane);
#pragma unroll
    for (int c = 0; c < 4; c++)
        gload_lds16(gB + (size_t)8 * c * K, &S[0][TM + 32 * wave + 8 * c][0], lane);

    for (int t = 0; t < NT; t++) {
        int cur = t & 1;
        if (t + 1 < NT) { // issue next tile, then wait only for current tile
            int k0 = (t + 1) * 64;
#pragma unroll
            for (int c = 0; c < AC; c++)
                gload_lds16(gA + (size_t)8 * c * K + k0, &S[cur ^ 1][(TM / 4) * wave + 8 * c][0], lane);
#pragma unroll
            for (int c = 0; c < 4; c++)
                gload_lds16(gB + (size_t)8 * c * K + k0, &S[cur ^ 1][TM + 32 * wave + 8 * c][0], lane);
            if constexpr (TM == 128)
                asm volatile("s_waitcnt vmcnt(8)" ::: "memory");
            else
                asm volatile("s_waitcnt vmcnt(6)" ::: "memory");
        } else {
            asm volatile("s_waitcnt vmcnt(0)" ::: "memory");
        }
        __builtin_amdgcn_s_barrier(); // all waves' tile-t loads landed

        unsigned short (*Sl)[64] = S[cur];
#pragma unroll
        for (int ks = 0; ks < 64; ks += 32) {
            bf16x8 af[NI], bfr[4];
#pragma unroll
            for (int i = 0; i < NI; i++)
                af[i] = *(const bf16x8*)&Sl[(TM / 2) * wr + 16 * i + l15][ks + 8 * quad];
#pragma unroll
            for (int j = 0; j < 4; j++)
                bfr[j] = *(const bf16x8*)&Sl[TM + 64 * wc + 16 * j + l15][ks + 8 * quad];
#pragma unroll
            for (int i = 0; i < NI; i++)
#pragma unroll
                for (int j = 0; j < 4; j++)
                    acc[i][j] = __builtin_amdgcn_mfma_f32_16x16x32_bf16(af[i], bfr[j], acc[i][j], 0, 0, 0);
        }
        asm volatile("" ::: "memory");    // pin LDS reads above the barrier
        __builtin_amdgcn_s_barrier();     // safe to overwrite buf[cur] next iter
    }

    if constexpr (!QKV) {
#pragma unroll
        for (int j = 0; j < 4; j++) {
            int nn = nb0 + 64 * wc + 16 * j + l15;
            float bv = bias[nn];
#pragma unroll
            for (int i = 0; i < NI; i++)
#pragma unroll
                for (int r = 0; r < 4; r++) {
                    int m = m0 + (TM / 2) * wr + 16 * i + 4 * quad + r;
                    ((float*)O0)[(size_t)m * DM + nn] = acc[i][j][r] + bv;
                }
        }
    } else {
        float sc = mi == 0 ? QSCALE : 1.0f; // bake softmax scale+log2e into Q
        __syncthreads();
        unsigned short (*Cl)[128] = (unsigned short(*)[128])S; // 128x128, fits
#pragma unroll
        for (int j = 0; j < 4; j++) {
            float bv = bias[nb0 + 64 * wc + 16 * j + l15];
#pragma unroll
            for (int i = 0; i < NI; i++)
#pragma unroll
                for (int r = 0; r < 4; r++)
                    Cl[(TM / 2) * wr + 16 * i + 4 * quad + r][64 * wc + 16 * j + l15] =
                        f2bf((acc[i][j][r] + bv) * sc);
        }
        __syncthreads();
        int row = tid >> 1, half = tid & 1; // QKV is TM=128 only (proven path)
        int m = m0 + row;
        int b = m >> 11, s = m & 2047;
        int h = (nb0 + 64 * half) >> 6;
        unsigned short* og = (unsigned short*)O + ((size_t)(b * H_ + h) * SEQ + s) * DK_;
        const unsigned short* cr = &Cl[row][64 * half];
#pragma unroll
        for (int c = 0; c < 4; c++)
            *(uint4*)(og + 16 * c) = *(const uint4*)(cr + 16 * c);
#pragma unroll
        for (int c = 0; c < 4; c++)
            *(uint4*)(og + 16 * c + 8) = *(const uint4*)(cr + 16 * c + 8);
    }
}

// ---------------- flash attention over COMPACTED keys, 2x2 wave split ---------
// Denominator via ones-vector MFMA: lsum[r] = sum_k p[q=qrl(r,hi)][k], same C/D
// row layout as o — no cross-lane shuffles; num/denom use identical bf16 p.
// XCD-bh swizzle: xcd = L&7 owns bh in {3x, 3x+1, 3x+2} -> K/V L2-resident.
__global__ __launch_bounds__(256) void attn_fa(const unsigned short* __restrict__ Q,
                                               const unsigned short* __restrict__ Kc,
                                               const unsigned short* __restrict__ Vtc,
                                               const int* __restrict__ nkeys,
                                               unsigned short* __restrict__ ctx) {
    __shared__ __align__(16) unsigned short Ql[64][72];
    __shared__ __align__(16) unsigned short Kl[64][72];
    __shared__ __align__(16) unsigned short Vl[64][68];
    __shared__ __align__(16) float Op[2][32][32]; // epilogue partials, per d-half
    __shared__ __align__(16) float lp[2][32];     // kh=1 partial row sums
    int tid = threadIdx.x;
    int wave = tid >> 6, lane = tid & 63;
    int l31 = lane & 31, hi = lane >> 5;
    int qh = wave & 1, kh = wave >> 1; // q-half, key-half

    // bijective XCD-grouping remap: dispatch round-robins L%8 across XCDs, so
    // give each xcd 3 full bh groups (1.5MB K/V, fits 4MB per-XCD L2).
    int L = blockIdx.y * gridDim.x + blockIdx.x; // 768 blocks
    int xcd = L & 7, rr = L >> 3;                // rr in [0,96)
    int bh = xcd * 3 + (rr >> 5);                // 3 bh per xcd
    int q0 = (rr & 31) * 64;
    int b = bh / H_, h = bh % H_;

    int n = nkeys[b];
    int nt = (n + 63) >> 6;            // compacted key tiles
    float padf = (float)(nt * 64 - n); // zero-pad rows contribute p=1 each

    { // stage Q tile (64x64) once
        int row = tid >> 2, cb = (tid & 3) * 16;
        const unsigned short* gq = Q + ((size_t)bh * SEQ + q0 + row) * DK_ + cb;
        *(uint4*)&Ql[row][cb]     = *(const uint4*)gq;
        *(uint4*)&Ql[row][cb + 8] = *(const uint4*)(gq + 8);
    }
    __syncthreads(); // Ql staged

    // loop-invariant Q fragments (queries 32*qh + l31)
    bf16x8 qf[4];
#pragma unroll
    for (int c = 0; c < 4; c++)
        qf[c] = *(const bf16x8*)&Ql[32 * qh + l31][16 * c + 8 * hi];

    union { unsigned u[2]; bf16x4 v; } onesu;
    onesu.u[0] = 0x3F803F80u; onesu.u[1] = 0x3F803F80u; // bf16 1.0 x4
    bf16x4 ones = onesu.v;

    f32x16 o[2][2]; // [d-half][ilp]
    f32x16 lsum;    // row sums of p (denominator), same row layout as o
#pragma unroll
    for (int r = 0; r < 16; r++) lsum[r] = 0.f;
#pragma unroll
    for (int dt = 0; dt < 2; dt++)
#pragma unroll
        for (int p = 0; p < 2; p++)
#pragma unroll
            for (int r = 0; r < 16; r++) o[dt][p][r] = 0.f;

    int krow = tid >> 2, kcb = (tid & 3) * 16;
    const unsigned short* gk = Kc + ((size_t)bh * SEQ + krow) * DK_ + kcb;
    const unsigned short* gv = Vtc + ((size_t)bh * DK_ + krow) * SEQ + kcb;

    // prefetch iter 0
    uint4 kr0 = *(const uint4*)gk, kr1 = *(const uint4*)(gk + 8);
    uint4 vr0 = *(const uint4*)gv, vr1 = *(const uint4*)(gv + 8);

    for (int kt = 0; kt < nt; kt++) {
        __syncthreads(); // prev iter's K/V LDS reads done
        *(uint4*)&Kl[krow][kcb]     = kr0;
        *(uint4*)&Kl[krow][kcb + 8] = kr1;
        *(uint4*)&Vl[krow][kcb]     = vr0;
        *(uint4*)&Vl[krow][kcb + 8] = vr1;
        __syncthreads(); // tiles visible
        if (kt + 1 < nt) { // prefetch next (latency hidden under compute)
            gk += (size_t)64 * DK_;
            gv += 64;
            kr0 = *(const uint4*)gk; kr1 = *(const uint4*)(gk + 8);
            vr0 = *(const uint4*)gv; vr1 = *(const uint4*)(gv + 8);
        }

        // S^T = K.Q^T (32 keys x 32 queries for this wave); zero C-init, no mask
        f32x16 sT;
#pragma unroll
        for (int r = 0; r < 16; r++) sT[r] = 0.f;
        __builtin_amdgcn_s_setprio(1);
#pragma unroll
        for (int c = 0; c < 4; c++) {
            bf16x8 kf = *(const bf16x8*)&Kl[32 * kh + l31][16 * c + 8 * hi];
            sT = __builtin_amdgcn_mfma_f32_32x32x16_bf16(kf, qf[c], sT, 0, 0, 0);
        }
        __builtin_amdgcn_s_setprio(0);

        // p = 2^s (scale pre-baked into Q): regs ARE the PV MFMA A-operand
        bf16x4 pfrag[4];
#pragma unroll
        for (int c = 0; c < 4; c++) {
            float p0 = exp2fast(sT[4 * c + 0]);
            float p1 = exp2fast(sT[4 * c + 1]);
            float p2 = exp2fast(sT[4 * c + 2]);
            float p3 = exp2fast(sT[4 * c + 3]);
            union { unsigned u[2]; bf16x4 v; } pk;
            pk.u[0] = pack2bf(p0, p1);
            pk.u[1] = pack2bf(p2, p3);
            pfrag[c] = pk.v;
        }

        __builtin_amdgcn_s_setprio(1);
        // denominator row sums on the MFMA pipe (B = ones)
#pragma unroll
        for (int c = 0; c < 4; c++)
            lsum = mfma32x8(pfrag[c], ones, lsum);

        // O[q][d] += P.V over this wave's 32 keys
#pragma unroll
        for (int dt = 0; dt < 2; dt++)
#pragma unroll
            for (int c = 0; c < 4; c++) {
                bf16x4 vf = *(const bf16x4*)&Vl[32 * dt + l31][32 * kh + 8 * c + 4 * hi];
                o[dt][c & 1] = mfma32x8(pfrag[c], vf, o[dt][c & 1]);
            }
        __builtin_amdgcn_s_setprio(0);
    }

    // combine across key-half wave pairs (two d-half chunks through Op), store
#pragma unroll
    for (int dt = 0; dt < 2; dt++) {
        if (kh == 1) {
#pragma unroll
            for (int r = 0; r < 16; r++) {
                int qrl = (r & 3) + 8 * (r >> 2) + 4 * hi;
                Op[qh][qrl][l31] = o[dt][0][r] + o[dt][1][r];
                if (dt == 0 && l31 == 0) lp[qh][qrl] = lsum[r];
            }
        }
        __syncthreads();
        if (kh == 0) {
#pragma unroll
            for (int r = 0; r < 16; r++) {
                int qrl = (r & 3) + 8 * (r >> 2) + 4 * hi;
                float l = lsum[r] + lp[qh][qrl] - padf; // remove pad-row p=1 terms
                float iv = l > 0.f ? 1.f / l : 0.f;
                int qg = q0 + 32 * qh + qrl;
                size_t base = ((size_t)b * SEQ + qg) * DM + h * DK_;
                float v = o[dt][0][r] + o[dt][1][r] + Op[qh][qrl][l31];
                ctx[base + 32 * dt + l31] = f2bf(v * iv);
            }
        }
        __syncthreads(); // Op safe for next chunk
    }
}

extern "C" void kernel_launch(void* const* d_in, const int* in_sizes, int n_in,
                              void* d_out, int out_size, void* d_ws, size_t ws_size,
                              hipStream_t stream) {
    const float* q  = (const float*)d_in[0];
    const float* k  = (const float*)d_in[1];
    const float* v  = (const float*)d_in[2];
    const float* Wq = (const float*)d_in[3];
    const float* bq = (const float*)d_in[4];
    const float* Wk = (const float*)d_in[5];
    const float* bk = (const float*)d_in[6];
    const float* Wv = (const float*)d_in[7];
    const float* bv = (const float*)d_in[8];
    const float* Wo = (const float*)d_in[9];
    const float* bo = (const float*)d_in[10];
    const int* mask = (const int*)d_in[11];

    unsigned short* ws = (unsigned short*)d_ws;
    unsigned short* qb = ws;
    unsigned short* kb = ws + PER_IN;
    unsigned short* vb = ws + 2 * PER_IN;
    unsigned short* Qh = ws + 3 * PER_IN;
    unsigned short* Kh = ws + 4 * PER_IN;
    unsigned short* Vhn = ws + 5 * PER_IN;
    unsigned short* WtQKV = ws + 6 * PER_IN;
    unsigned short* WtO = WtQKV + (size_t)3 * DM * DM;
    unsigned short* Kc = kb;   // kb dead after QKV GEMM
    unsigned short* Vtc = vb;  // vb dead after QKV GEMM
    unsigned short* ctx = qb;  // qb dead after QKV GEMM
    int* idx = (int*)d_out;    // dead until final GEMM overwrites d_out
    int* nk = idx + B_DIM * SEQ;

    prep<<<dim3(11522), 256, 0, stream>>>(q, k, v, qb, kb, vb,
                                          Wq, Wk, Wv, Wo, WtQKV, mask, idx, nk);

    gemm128<1, 128><<<dim3(MROWS / 128, 3 * DM / 128), 256, 0, stream>>>(
        qb, kb, vb, WtQKV, bq, bk, bv, Qh, Kh, Vhn);

    gatherKV<<<dim3(SEQ / 64, B_DIM * H_), 256, 0, stream>>>(Kh, Vhn, idx, nk, Kc, Vtc);

    attn_fa<<<dim3(SEQ / 64, B_DIM * H_), 256, 0, stream>>>(Qh, Kc, Vtc, nk, ctx);

    gemm128<0, 64><<<dim3(MROWS / 64, DM / 128), 256, 0, stream>>>(
        ctx, ctx, ctx, WtO, bo, bo, bo, d_out, d_out, d_out);
}

// Round 11
// 197.193 us; speedup vs baseline: 1.0163x; 1.0163x over previous
//
#include <hip/hip_runtime.h>

// Multi-head attention, B=2 S=2048 D=768 H=12 DK=64. I/O fp32, internal bf16 MFMA.
// Round 18: REVERT round-17's attn hints — counters convicted BOTH:
//   attn 62us (R8 bound: <=44us) with FETCH 6.3MB (= compact K/V, so the XCD-bh
//   swizzle DID make K/V L2-resident) and HBM 2.5% -> memory was never the attn
//   bottleneck; the swizzle+setprio pair added a ~20us execution stall (setprio
//   convoy in barrier-locked 4-wave blocks = m190 lockstep-null case; same-addr
//   L2 lockstep contention from 32 co-resident same-bh blocks). Banked: neither
//   T1 nor T5 applies to this lockstep attn shape.
// Forward (orthogonal, zero-risk): prep cvt widened to 8 floats/thread
// (32B/lane reads; cvt blocks 9216->4608, prep grid 11522->6914).
// R16 lesson: fillBufferAligned = constant-work clock probe; normalize walls.
// R15: plain launch_bounds on attn ((256,4) caused 64-VGPR spills). Keep:
// lsum-via-MFMA denominator (bank conflicts 49K->0), TM=64 out-proj, XCD
// swizzle on GEMMs. R13: gatherKV once, streaming. R10: GEMM 2-phase pipeline
// (dbuf LDS + counted vmcnt + raw s_barrier). R9: mask compaction; no mask path
// in attn (zero pads -> p=1, corrected in denominator); Q pre-scaled by
// 0.125*log2(e) -> softmax is raw v_exp_f32.
// Replay-hardening: idx/nk scratch in d_out; no early return before barriers;
// no inline-asm transcendentals. attn LDS strides 72/68 proven conflict-free.

#define H_ 12
#define DK_ 64
#define B_DIM 2
#define SEQ 2048
#define DM 768
#define MROWS 4096
#define PER_IN ((size_t)MROWS * DM)
#define QSCALE 0.18033688011112042f

typedef short bf16x8 __attribute__((ext_vector_type(8)));
typedef short bf16x4 __attribute__((ext_vector_type(4)));
typedef float f32x4 __attribute__((ext_vector_type(4)));
typedef float f32x16 __attribute__((ext_vector_type(16)));

__device__ inline unsigned short f2bf(float f) {
    union { float f; unsigned int i; } x; x.f = f;
    unsigned int r = x.i + 0x7fff + ((x.i >> 16) & 1); // RNE
    return (unsigned short)(r >> 16);
}

__device__ inline unsigned pack2bf(float lo, float hi) {
#if __has_builtin(__builtin_amdgcn_cvt_pk_bf16_f32)
    auto v = __builtin_amdgcn_cvt_pk_bf16_f32(lo, hi);
    return __builtin_bit_cast(unsigned, v);
#else
    return (unsigned)f2bf(lo) | ((unsigned)f2bf(hi) << 16);
#endif
}

__device__ inline float exp2fast(float x) { // 2^x
#if __has_builtin(__builtin_amdgcn_exp2f)
    return __builtin_amdgcn_exp2f(x);
#else
    return exp2f(x);
#endif
}

__device__ inline f32x16 mfma32x8(bf16x4 a, bf16x4 b, f32x16 c) {
#if __has_builtin(__builtin_amdgcn_mfma_f32_32x32x8bf16_1k)
    return __builtin_amdgcn_mfma_f32_32x32x8bf16_1k(a, b, c, 0, 0, 0);
#else
    asm("v_mfma_f32_32x32x8_bf16 %0, %1, %2, %0" : "+v"(c) : "v"(a), "v"(b));
    return c;
#endif
}

// async 16B/lane global->LDS; ldsbase must be wave-uniform (HW adds lane*16B)
__device__ inline void gload_lds16(const unsigned short* g, unsigned short* ldsbase,
                                   int lane) {
#if __has_builtin(__builtin_amdgcn_global_load_lds)
    __builtin_amdgcn_global_load_lds(
        (const __attribute__((address_space(1))) unsigned int*)g,
        (__attribute__((address_space(3))) unsigned int*)ldsbase, 16, 0, 0);
#else
    *(uint4*)(ldsbase + 8 * lane) = *(const uint4*)g;
#endif
}

// -------- prep: fp32->bf16 convert x3 (8 f/thr)  |  4 transposes  |  scan -----
// Flat 1D grid: [0,4608) cvt; [4608,6912) transpose; [6912,6914) maskscan.
__global__ __launch_bounds__(256) void prep(
    const float* __restrict__ q, const float* __restrict__ k,
    const float* __restrict__ v,
    unsigned short* __restrict__ qb, unsigned short* __restrict__ kb,
    unsigned short* __restrict__ vb,
    const float* __restrict__ w0, const float* __restrict__ w1,
    const float* __restrict__ w2, const float* __restrict__ w3,
    unsigned short* __restrict__ wtbase,
    const int* __restrict__ mask, int* __restrict__ idx,
    int* __restrict__ nkeys) {
    __shared__ unsigned short t[32][33];
    __shared__ int wsum[4];
    int job = blockIdx.x, tid = threadIdx.x;
    if (job < 4608) { // ---- convert, 8 floats / thread ----
        int buf = job / 1536, x = job % 1536;
        const float* src = buf == 0 ? q : (buf == 1 ? k : v);
        unsigned short* dst = buf == 0 ? qb : (buf == 1 ? kb : vb);
        size_t i = ((size_t)x * 256 + tid) * 8;
        float4 f0 = *(const float4*)(src + i);
        float4 f1 = *(const float4*)(src + i + 4);
        ushort4 u0, u1;
        u0.x = f2bf(f0.x); u0.y = f2bf(f0.y); u0.z = f2bf(f0.z); u0.w = f2bf(f0.w);
        u1.x = f2bf(f1.x); u1.y = f2bf(f1.y); u1.z = f2bf(f1.z); u1.w = f2bf(f1.w);
        *(ushort4*)(dst + i) = u0;
        *(ushort4*)(dst + i + 4) = u1;
    } else if (job < 6912) { // ---- weight transpose Wt[n][k] = bf16(W[k][n]) --
        int tb = job - 4608;
        int z = tb / 576, r = tb % 576, by = r / 24, bx = r % 24;
        const float* in = z == 0 ? w0 : (z == 1 ? w1 : (z == 2 ? w2 : w3));
        unsigned short* out = wtbase + (size_t)z * DM * DM;
        int x = tid & 31, y = tid >> 5; // 32 x 8
        int k0 = bx * 32, n0 = by * 32;
#pragma unroll
        for (int i = 0; i < 32; i += 8)
            t[y + i][x] = f2bf(in[(size_t)(k0 + y + i) * DM + n0 + x]);
        __syncthreads();
#pragma unroll
        for (int i = 0; i < 32; i += 8)
            out[(size_t)(n0 + y + i) * DM + k0 + x] = t[x][y + i];
    } else { // ---- mask scan: compact indices of unmasked keys ----
        int b = job - 6912;
        int lane = tid & 63, wave = tid >> 6;
        const int* mp = mask + (size_t)b * SEQ + tid * 8;
        int4 a = *(const int4*)mp;
        int4 c = *(const int4*)(mp + 4);
        int m[8] = {a.x, a.y, a.z, a.w, c.x, c.y, c.z, c.w};
        int pre[8], s = 0;
#pragma unroll
        for (int e = 0; e < 8; e++) { pre[e] = s; s += (m[e] != 0); }
        int incl = s;
#pragma unroll
        for (int off = 1; off < 64; off <<= 1) {
            int vv = __shfl_up(incl, off);
            if (lane >= off) incl += vv;
        }
        int lexcl = incl - s;
        if (lane == 63) wsum[wave] = incl;
        __syncthreads();
        int base = lexcl;
        for (int w = 0; w < wave; w++) base += wsum[w];
#pragma unroll
        for (int e = 0; e < 8; e++)
            if (m[e]) idx[b * SEQ + base + pre[e]] = tid * 8 + e;
        if (tid == 0) nkeys[b] = wsum[0] + wsum[1] + wsum[2] + wsum[3];
    }
}

// -------- gather compacted K rows + transposed V columns, zero-padded --------
__global__ __launch_bounds__(256) void gatherKV(const unsigned short* __restrict__ Kh,
                                                const unsigned short* __restrict__ Vn,
                                                const int* __restrict__ idx,
                                                const int* __restrict__ nkeys,
                                                unsigned short* __restrict__ Kc,
                                                unsigned short* __restrict__ Vtc) {
    __shared__ unsigned short Tl[64][72];
    int tid = threadIdx.x;
    int j0 = blockIdx.x * 64, bh = blockIdx.y, b = bh / H_;
    int n = nkeys[b];
    int row = tid >> 2, cb = (tid & 3) * 16;
    int j = j0 + row;
    int src = j < n ? idx[b * SEQ + j] : -1;
    unsigned short v[16];
    unsigned short* ok = Kc + ((size_t)bh * SEQ + j) * DK_ + cb;
    if (src >= 0) {
        const unsigned short* gv = Vn + ((size_t)bh * SEQ + src) * DK_ + cb;
        *(uint4*)&v[0] = *(const uint4*)gv;
        *(uint4*)&v[8] = *(const uint4*)(gv + 8);
        const unsigned short* gk = Kh + ((size_t)bh * SEQ + src) * DK_ + cb;
        uint4 k0 = *(const uint4*)gk;
        uint4 k1 = *(const uint4*)(gk + 8);
        *(uint4*)ok = k0;
        *(uint4*)(ok + 8) = k1;
    } else { // pad/tail: zero K row and V row -> s=0, p=1 (corrected), p*V=0
        uint4 z = {0u, 0u, 0u, 0u};
        *(uint4*)&v[0] = z;
        *(uint4*)&v[8] = z;
        *(uint4*)ok = z;
        *(uint4*)(ok + 8) = z;
    }
#pragma unroll
    for (int e = 0; e < 16; e++)
        Tl[cb + e][row] = v[e];
    __syncthreads();
    uint4 o0 = *(const uint4*)&Tl[row][cb];
    uint4 o1 = *(const uint4*)&Tl[row][cb + 8];
    unsigned short* out = Vtc + ((size_t)bh * DK_ + row) * SEQ + j0 + cb;
    *(uint4*)out = o0;
    *(uint4*)(out + 8) = o1;
}

// ------------- GEMM: C[m][n] = A[m][:] . Wt[n][:] + bias[n], TM x 128 --------
// 2-phase pipeline: LDS double-buffer; stage(t+1) issued BEFORE waiting on
// tile t (counted vmcnt = next tile's loads in flight); raw s_barrier.
// TM=128: 8 loads/wave/stage, 64KB, 2 blk/CU. TM=64: 6 loads, 48KB, 3 blk/CU.
template <int QKV, int TM>
__global__ __launch_bounds__(256) void gemm128(
    const unsigned short* __restrict__ A0, const unsigned short* __restrict__ A1,
    const unsigned short* __restrict__ A2, const unsigned short* __restrict__ Wt,
    const float* __restrict__ bias0, const float* __restrict__ bias1,
    const float* __restrict__ bias2,
    void* __restrict__ O0, void* __restrict__ O1, void* __restrict__ O2) {
    __shared__ unsigned short S[2][TM + 128][64]; // rows [0,TM)=A, [TM,TM+128)=B
    const int K = DM;
    const int NT = K / 64; // 12
    constexpr int NI = TM / 32; // acc row-frags per wave
    constexpr int AC = TM / 32; // A-stage instrs per wave
    int tid = threadIdx.x;
    int wave = tid >> 6, lane = tid & 63, quad = lane >> 4, l15 = lane & 15;
    int wr = wave >> 1, wc = wave & 1;

    // XCD-aware bijective swizzle (nwg % 8 == 0 for both grids)
    int nwg = gridDim.x * gridDim.y;
    int lin = blockIdx.y * gridDim.x + blockIdx.x;
    int swz = (lin & 7) * (nwg >> 3) + (lin >> 3);
    int bx = swz % gridDim.x, by = swz / gridDim.x;
    int m0 = bx * TM, n0 = by * 128;
    int lrow = lane >> 3, lcol = (lane & 7) * 8;

    int mi = 0, nb0 = n0;
    const unsigned short* A = A0;
    const float* bias = bias0;
    void* O = O0;
    if constexpr (QKV) {
        mi = n0 >= 1536 ? 2 : (n0 >= 768 ? 1 : 0);
        nb0 = n0 - mi * 768;
        A = mi == 0 ? A0 : (mi == 1 ? A1 : A2);
        bias = mi == 0 ? bias0 : (mi == 1 ? bias1 : bias2);
        O = mi == 0 ? O0 : (mi == 1 ? O1 : O2);
    }

    f32x4 acc[NI][4];
#pragma unroll
    for (int i = 0; i < NI; i++)
#pragma unroll
        for (int j = 0; j < 4; j++)
#pragma unroll
            for (int r = 0; r < 4; r++) acc[i][j][r] = 0.f;

    const unsigned short* gA = A + (size_t)(m0 + (TM / 4) * wave + lrow) * K + lcol;
    const unsigned short* gB = Wt + (size_t)(n0 + 32 * wave + lrow) * K + lcol;

    // prologue: stage tile 0 into buf 0
#pragma unroll
    for (int c = 0; c < AC; c++)
        gload_lds16(gA + (size_t)8 * c * K, &S[0][(TM / 4) * wave + 8 * c][0], lane);
#pragma unroll
    for (int c = 0; c < 4; c++)
        gload_lds16(gB + (size_t)8 * c * K, &S[0][TM + 32 * wave + 8 * c][0], lane);

    for (int t = 0; t < NT; t++) {
        int cur = t & 1;
        if (t + 1 < NT) { // issue next tile, then wait only for current tile
            int k0 = (t + 1) * 64;
#pragma unroll
            for (int c = 0; c < AC; c++)
                gload_lds16(gA + (size_t)8 * c * K + k0, &S[cur ^ 1][(TM / 4) * wave + 8 * c][0], lane);
#pragma unroll
            for (int c = 0; c < 4; c++)
                gload_lds16(gB + (size_t)8 * c * K + k0, &S[cur ^ 1][TM + 32 * wave + 8 * c][0], lane);
            if constexpr (TM == 128)
                asm volatile("s_waitcnt vmcnt(8)" ::: "memory");
            else
                asm volatile("s_waitcnt vmcnt(6)" ::: "memory");
        } else {
            asm volatile("s_waitcnt vmcnt(0)" ::: "memory");
        }
        __builtin_amdgcn_s_barrier(); // all waves' tile-t loads landed

        unsigned short (*Sl)[64] = S[cur];
#pragma unroll
        for (int ks = 0; ks < 64; ks += 32) {
            bf16x8 af[NI], bfr[4];
#pragma unroll
            for (int i = 0; i < NI; i++)
                af[i] = *(const bf16x8*)&Sl[(TM / 2) * wr + 16 * i + l15][ks + 8 * quad];
#pragma unroll
            for (int j = 0; j < 4; j++)
                bfr[j] = *(const bf16x8*)&Sl[TM + 64 * wc + 16 * j + l15][ks + 8 * quad];
#pragma unroll
            for (int i = 0; i < NI; i++)
#pragma unroll
                for (int j = 0; j < 4; j++)
                    acc[i][j] = __builtin_amdgcn_mfma_f32_16x16x32_bf16(af[i], bfr[j], acc[i][j], 0, 0, 0);
        }
        asm volatile("" ::: "memory");    // pin LDS reads above the barrier
        __builtin_amdgcn_s_barrier();     // safe to overwrite buf[cur] next iter
    }

    if constexpr (!QKV) {
#pragma unroll
        for (int j = 0; j < 4; j++) {
            int nn = nb0 + 64 * wc + 16 * j + l15;
            float bv = bias[nn];
#pragma unroll
            for (int i = 0; i < NI; i++)
#pragma unroll
                for (int r = 0; r < 4; r++) {
                    int m = m0 + (TM / 2) * wr + 16 * i + 4 * quad + r;
                    ((float*)O0)[(size_t)m * DM + nn] = acc[i][j][r] + bv;
                }
        }
    } else {
        float sc = mi == 0 ? QSCALE : 1.0f; // bake softmax scale+log2e into Q
        __syncthreads();
        unsigned short (*Cl)[128] = (unsigned short(*)[128])S; // 128x128, fits
#pragma unroll
        for (int j = 0; j < 4; j++) {
            float bv = bias[nb0 + 64 * wc + 16 * j + l15];
#pragma unroll
            for (int i = 0; i < NI; i++)
#pragma unroll
                for (int r = 0; r < 4; r++)
                    Cl[(TM / 2) * wr + 16 * i + 4 * quad + r][64 * wc + 16 * j + l15] =
                        f2bf((acc[i][j][r] + bv) * sc);
        }
        __syncthreads();
        int row = tid >> 1, half = tid & 1; // QKV is TM=128 only (proven path)
        int m = m0 + row;
        int b = m >> 11, s = m & 2047;
        int h = (nb0 + 64 * half) >> 6;
        unsigned short* og = (unsigned short*)O + ((size_t)(b * H_ + h) * SEQ + s) * DK_;
        const unsigned short* cr = &Cl[row][64 * half];
#pragma unroll
        for (int c = 0; c < 4; c++)
            *(uint4*)(og + 16 * c) = *(const uint4*)(cr + 16 * c);
#pragma unroll
        for (int c = 0; c < 4; c++)
            *(uint4*)(og + 16 * c + 8) = *(const uint4*)(cr + 16 * c + 8);
    }
}

// ---------------- flash attention over COMPACTED keys, 2x2 wave split ---------
// Denominator via ones-vector MFMA: lsum[r] = sum_k p[q=qrl(r,hi)][k], same C/D
// row layout as o — no cross-lane shuffles; num/denom use identical bf16 p.
// R18: exact R8 body — no setprio, no bh-remap (both measured harmful, R17).
__global__ __launch_bounds__(256) void attn_fa(const unsigned short* __restrict__ Q,
                                               const unsigned short* __restrict__ Kc,
                                               const unsigned short* __restrict__ Vtc,
                                               const int* __restrict__ nkeys,
                                               unsigned short* __restrict__ ctx) {
    __shared__ __align__(16) unsigned short Ql[64][72];
    __shared__ __align__(16) unsigned short Kl[64][72];
    __shared__ __align__(16) unsigned short Vl[64][68];
    __shared__ __align__(16) float Op[2][32][32]; // epilogue partials, per d-half
    __shared__ __align__(16) float lp[2][32];     // kh=1 partial row sums
    int tid = threadIdx.x;
    int wave = tid >> 6, lane = tid & 63;
    int l31 = lane & 31, hi = lane >> 5;
    int qh = wave & 1, kh = wave >> 1; // q-half, key-half
    int bh = blockIdx.y, b = bh / H_, h = bh % H_;
    int q0 = blockIdx.x * 64;

    int n = nkeys[b];
    int nt = (n + 63) >> 6;            // compacted key tiles
    float padf = (float)(nt * 64 - n); // zero-pad rows contribute p=1 each

    { // stage Q tile (64x64) once
        int row = tid >> 2, cb = (tid & 3) * 16;
        const unsigned short* gq = Q + ((size_t)bh * SEQ + q0 + row) * DK_ + cb;
        *(uint4*)&Ql[row][cb]     = *(const uint4*)gq;
        *(uint4*)&Ql[row][cb + 8] = *(const uint4*)(gq + 8);
    }
    __syncthreads(); // Ql staged

    // loop-invariant Q fragments (queries 32*qh + l31)
    bf16x8 qf[4];
#pragma unroll
    for (int c = 0; c < 4; c++)
        qf[c] = *(const bf16x8*)&Ql[32 * qh + l31][16 * c + 8 * hi];

    union { unsigned u[2]; bf16x4 v; } onesu;
    onesu.u[0] = 0x3F803F80u; onesu.u[1] = 0x3F803F80u; // bf16 1.0 x4
    bf16x4 ones = onesu.v;

    f32x16 o[2][2]; // [d-half][ilp]
    f32x16 lsum;    // row sums of p (denominator), same row layout as o
#pragma unroll
    for (int r = 0; r < 16; r++) lsum[r] = 0.f;
#pragma unroll
    for (int dt = 0; dt < 2; dt++)
#pragma unroll
        for (int p = 0; p < 2; p++)
#pragma unroll
            for (int r = 0; r < 16; r++) o[dt][p][r] = 0.f;

    int krow = tid >> 2, kcb = (tid & 3) * 16;
    const unsigned short* gk = Kc + ((size_t)bh * SEQ + krow) * DK_ + kcb;
    const unsigned short* gv = Vtc + ((size_t)bh * DK_ + krow) * SEQ + kcb;

    // prefetch iter 0
    uint4 kr0 = *(const uint4*)gk, kr1 = *(const uint4*)(gk + 8);
    uint4 vr0 = *(const uint4*)gv, vr1 = *(const uint4*)(gv + 8);

    for (int kt = 0; kt < nt; kt++) {
        __syncthreads(); // prev iter's K/V LDS reads done
        *(uint4*)&Kl[krow][kcb]     = kr0;
        *(uint4*)&Kl[krow][kcb + 8] = kr1;
        *(uint4*)&Vl[krow][kcb]     = vr0;
        *(uint4*)&Vl[krow][kcb + 8] = vr1;
        __syncthreads(); // tiles visible
        if (kt + 1 < nt) { // prefetch next (latency hidden under compute)
            gk += (size_t)64 * DK_;
            gv += 64;
            kr0 = *(const uint4*)gk; kr1 = *(const uint4*)(gk + 8);
            vr0 = *(const uint4*)gv; vr1 = *(const uint4*)(gv + 8);
        }

        // S^T = K.Q^T (32 keys x 32 queries for this wave); zero C-init, no mask
        f32x16 sT;
#pragma unroll
        for (int r = 0; r < 16; r++) sT[r] = 0.f;
#pragma unroll
        for (int c = 0; c < 4; c++) {
            bf16x8 kf = *(const bf16x8*)&Kl[32 * kh + l31][16 * c + 8 * hi];
            sT = __builtin_amdgcn_mfma_f32_32x32x16_bf16(kf, qf[c], sT, 0, 0, 0);
        }

        // p = 2^s (scale pre-baked into Q): regs ARE the PV MFMA A-operand
        bf16x4 pfrag[4];
#pragma unroll
        for (int c = 0; c < 4; c++) {
            float p0 = exp2fast(sT[4 * c + 0]);
            float p1 = exp2fast(sT[4 * c + 1]);
            float p2 = exp2fast(sT[4 * c + 2]);
            float p3 = exp2fast(sT[4 * c + 3]);
            union { unsigned u[2]; bf16x4 v; } pk;
            pk.u[0] = pack2bf(p0, p1);
            pk.u[1] = pack2bf(p2, p3);
            pfrag[c] = pk.v;
        }

        // denominator row sums on the MFMA pipe (B = ones)
#pragma unroll
        for (int c = 0; c < 4; c++)
            lsum = mfma32x8(pfrag[c], ones, lsum);

        // O[q][d] += P.V over this wave's 32 keys
#pragma unroll
        for (int dt = 0; dt < 2; dt++)
#pragma unroll
            for (int c = 0; c < 4; c++) {
                bf16x4 vf = *(const bf16x4*)&Vl[32 * dt + l31][32 * kh + 8 * c + 4 * hi];
                o[dt][c & 1] = mfma32x8(pfrag[c], vf, o[dt][c & 1]);
            }
    }

    // combine across key-half wave pairs (two d-half chunks through Op), store
#pragma unroll
    for (int dt = 0; dt < 2; dt++) {
        if (kh == 1) {
#pragma unroll
            for (int r = 0; r < 16; r++) {
                int qrl = (r & 3) + 8 * (r >> 2) + 4 * hi;
                Op[qh][qrl][l31] = o[dt][0][r] + o[dt][1][r];
                if (dt == 0 && l31 == 0) lp[qh][qrl] = lsum[r];
            }
        }
        __syncthreads();
        if (kh == 0) {
#pragma unroll
            for (int r = 0; r < 16; r++) {
                int qrl = (r & 3) + 8 * (r >> 2) + 4 * hi;
                float l = lsum[r] + lp[qh][qrl] - padf; // remove pad-row p=1 terms
                float iv = l > 0.f ? 1.f / l : 0.f;
                int qg = q0 + 32 * qh + qrl;
                size_t base = ((size_t)b * SEQ + qg) * DM + h * DK_;
                float v = o[dt][0][r] + o[dt][1][r] + Op[qh][qrl][l31];
                ctx[base + 32 * dt + l31] = f2bf(v * iv);
            }
        }
        __syncthreads(); // Op safe for next chunk
    }
}

extern "C" void kernel_launch(void* const* d_in, const int* in_sizes, int n_in,
                              void* d_out, int out_size, void* d_ws, size_t ws_size,
                              hipStream_t stream) {
    const float* q  = (const float*)d_in[0];
    const float* k  = (const float*)d_in[1];
    const float* v  = (const float*)d_in[2];
    const float* Wq = (const float*)d_in[3];
    const float* bq = (const float*)d_in[4];
    const float* Wk = (const float*)d_in[5];
    const float* bk = (const float*)d_in[6];
    const float* Wv = (const float*)d_in[7];
    const float* bv = (const float*)d_in[8];
    const float* Wo = (const float*)d_in[9];
    const float* bo = (const float*)d_in[10];
    const int* mask = (const int*)d_in[11];

    unsigned short* ws = (unsigned short*)d_ws;
    unsigned short* qb = ws;
    unsigned short* kb = ws + PER_IN;
    unsigned short* vb = ws + 2 * PER_IN;
    unsigned short* Qh = ws + 3 * PER_IN;
    unsigned short* Kh = ws + 4 * PER_IN;
    unsigned short* Vhn = ws + 5 * PER_IN;
    unsigned short* WtQKV = ws + 6 * PER_IN;
    unsigned short* WtO = WtQKV + (size_t)3 * DM * DM;
    unsigned short* Kc = kb;   // kb dead after QKV GEMM
    unsigned short* Vtc = vb;  // vb dead after QKV GEMM
    unsigned short* ctx = qb;  // qb dead after QKV GEMM
    int* idx = (int*)d_out;    // dead until final GEMM overwrites d_out
    int* nk = idx + B_DIM * SEQ;

    // prep: 4608 cvt blocks + 2304 transpose blocks + 2 scan blocks
    prep<<<dim3(6914), 256, 0, stream>>>(q, k, v, qb, kb, vb,
                                         Wq, Wk, Wv, Wo, WtQKV, mask, idx, nk);

    gemm128<1, 128><<<dim3(MROWS / 128, 3 * DM / 128), 256, 0, stream>>>(
        qb, kb, vb, WtQKV, bq, bk, bv, Qh, Kh, Vhn);

    gatherKV<<<dim3(SEQ / 64, B_DIM * H_), 256, 0, stream>>>(Kh, Vhn, idx, nk, Kc, Vtc);

    attn_fa<<<dim3(SEQ / 64, B_DIM * H_), 256, 0, stream>>>(Qh, Kc, Vtc, nk, ctx);

    gemm128<0, 64><<<dim3(MROWS / 64, DM / 128), 256, 0, stream>>>(
        ctx, ctx, ctx, WtO, bo, bo, bo, d_out, d_out, d_out);
}

// Round 12
// 195.270 us; speedup vs baseline: 1.0263x; 1.0098x over previous
//
#include <hip/hip_runtime.h>

// Multi-head attention, B=2 S=2048 D=768 H=12 DK=64. I/O fp32, internal bf16 MFMA.
// Round 19: kill the K round-trip. Softmax is permutation-invariant over keys,
// so the QKV GEMM epilogue writes K AND V rows directly in COMPACTED order via
// pos[s] (maskscan's inverse-rank map: unmasked->rank, masked->n+maskedrank;
// bijective -> every row written once, deterministic). gatherKV shrinks to
// gatherV: sequential compact-V transpose (no idx indirection) + zeroing the
// <=63 K pad rows [n, ceil64(n)) that attn reads. Compact order identical to
// the old idx order -> attn math bitwise unchanged. K compact buffer = old Kh
// slot (no aliasing with GEMM input kb). Saves ~19MB HBM traffic + half the
// gather kernel. QKV MFMA/staging geometry untouched (TM=128 proven path);
// attn untouched (R18 = R8 body).
// R17 lesson (counters): attn is NOT memory-bound (FETCH 6.3MB run was SLOWER);
// XCD-bh swizzle + setprio both harmful on lockstep attn. R16: fill dispatches
// = constant-work clock probe; normalize cross-round walls. R15: no VGPR-capping
// launch_bounds on attn. R10: GEMM 2-phase pipeline (dbuf LDS + counted vmcnt +
// raw s_barrier). R9: mask compaction; no mask path in attn (zero pads -> p=1,
// corrected in denominator); Q pre-scaled 0.125*log2(e) -> raw v_exp_f32.
// Replay-hardening: pos/nk scratch in d_out; no early return before barriers;
// no inline-asm transcendentals. attn LDS strides 72/68 proven conflict-free.

#define H_ 12
#define DK_ 64
#define B_DIM 2
#define SEQ 2048
#define DM 768
#define MROWS 4096
#define PER_IN ((size_t)MROWS * DM)
#define QSCALE 0.18033688011112042f

typedef short bf16x8 __attribute__((ext_vector_type(8)));
typedef short bf16x4 __attribute__((ext_vector_type(4)));
typedef float f32x4 __attribute__((ext_vector_type(4)));
typedef float f32x16 __attribute__((ext_vector_type(16)));

__device__ inline unsigned short f2bf(float f) {
    union { float f; unsigned int i; } x; x.f = f;
    unsigned int r = x.i + 0x7fff + ((x.i >> 16) & 1); // RNE
    return (unsigned short)(r >> 16);
}

__device__ inline unsigned pack2bf(float lo, float hi) {
#if __has_builtin(__builtin_amdgcn_cvt_pk_bf16_f32)
    auto v = __builtin_amdgcn_cvt_pk_bf16_f32(lo, hi);
    return __builtin_bit_cast(unsigned, v);
#else
    return (unsigned)f2bf(lo) | ((unsigned)f2bf(hi) << 16);
#endif
}

__device__ inline float exp2fast(float x) { // 2^x
#if __has_builtin(__builtin_amdgcn_exp2f)
    return __builtin_amdgcn_exp2f(x);
#else
    return exp2f(x);
#endif
}

__device__ inline f32x16 mfma32x8(bf16x4 a, bf16x4 b, f32x16 c) {
#if __has_builtin(__builtin_amdgcn_mfma_f32_32x32x8bf16_1k)
    return __builtin_amdgcn_mfma_f32_32x32x8bf16_1k(a, b, c, 0, 0, 0);
#else
    asm("v_mfma_f32_32x32x8_bf16 %0, %1, %2, %0" : "+v"(c) : "v"(a), "v"(b));
    return c;
#endif
}

// async 16B/lane global->LDS; ldsbase must be wave-uniform (HW adds lane*16B)
__device__ inline void gload_lds16(const unsigned short* g, unsigned short* ldsbase,
                                   int lane) {
#if __has_builtin(__builtin_amdgcn_global_load_lds)
    __builtin_amdgcn_global_load_lds(
        (const __attribute__((address_space(1))) unsigned int*)g,
        (__attribute__((address_space(3))) unsigned int*)ldsbase, 16, 0, 0);
#else
    *(uint4*)(ldsbase + 8 * lane) = *(const uint4*)g;
#endif
}

// -------- prep: fp32->bf16 convert x3 (8 f/thr)  |  4 transposes  |  scan -----
// Flat 1D grid: [0,4608) cvt; [4608,6912) transpose; [6912,6914) maskscan.
// maskscan emits pos[s]: bijective compact map (unmasked->rank, masked->n+mrank).
__global__ __launch_bounds__(256) void prep(
    const float* __restrict__ q, const float* __restrict__ k,
    const float* __restrict__ v,
    unsigned short* __restrict__ qb, unsigned short* __restrict__ kb,
    unsigned short* __restrict__ vb,
    const float* __restrict__ w0, const float* __restrict__ w1,
    const float* __restrict__ w2, const float* __restrict__ w3,
    unsigned short* __restrict__ wtbase,
    const int* __restrict__ mask, int* __restrict__ pos,
    int* __restrict__ nkeys) {
    __shared__ unsigned short t[32][33];
    __shared__ int wsum[4];
    int job = blockIdx.x, tid = threadIdx.x;
    if (job < 4608) { // ---- convert, 8 floats / thread ----
        int buf = job / 1536, x = job % 1536;
        const float* src = buf == 0 ? q : (buf == 1 ? k : v);
        unsigned short* dst = buf == 0 ? qb : (buf == 1 ? kb : vb);
        size_t i = ((size_t)x * 256 + tid) * 8;
        float4 f0 = *(const float4*)(src + i);
        float4 f1 = *(const float4*)(src + i + 4);
        ushort4 u0, u1;
        u0.x = f2bf(f0.x); u0.y = f2bf(f0.y); u0.z = f2bf(f0.z); u0.w = f2bf(f0.w);
        u1.x = f2bf(f1.x); u1.y = f2bf(f1.y); u1.z = f2bf(f1.z); u1.w = f2bf(f1.w);
        *(ushort4*)(dst + i) = u0;
        *(ushort4*)(dst + i + 4) = u1;
    } else if (job < 6912) { // ---- weight transpose Wt[n][k] = bf16(W[k][n]) --
        int tb = job - 4608;
        int z = tb / 576, r = tb % 576, by = r / 24, bx = r % 24;
        const float* in = z == 0 ? w0 : (z == 1 ? w1 : (z == 2 ? w2 : w3));
        unsigned short* out = wtbase + (size_t)z * DM * DM;
        int x = tid & 31, y = tid >> 5; // 32 x 8
        int k0 = bx * 32, n0 = by * 32;
#pragma unroll
        for (int i = 0; i < 32; i += 8)
            t[y + i][x] = f2bf(in[(size_t)(k0 + y + i) * DM + n0 + x]);
        __syncthreads();
#pragma unroll
        for (int i = 0; i < 32; i += 8)
            out[(size_t)(n0 + y + i) * DM + k0 + x] = t[x][y + i];
    } else { // ---- mask scan: inverse-rank compact map ----
        int b = job - 6912;
        int lane = tid & 63, wave = tid >> 6;
        const int* mp = mask + (size_t)b * SEQ + tid * 8;
        int4 a = *(const int4*)mp;
        int4 c = *(const int4*)(mp + 4);
        int m[8] = {a.x, a.y, a.z, a.w, c.x, c.y, c.z, c.w};
        int pre[8], s = 0;
#pragma unroll
        for (int e = 0; e < 8; e++) { pre[e] = s; s += (m[e] != 0); }
        int incl = s;
#pragma unroll
        for (int off = 1; off < 64; off <<= 1) {
            int vv = __shfl_up(incl, off);
            if (lane >= off) incl += vv;
        }
        int lexcl = incl - s;
        if (lane == 63) wsum[wave] = incl;
        __syncthreads();
        int base = lexcl;
        for (int w = 0; w < wave; w++) base += wsum[w];
        int nq = wsum[0] + wsum[1] + wsum[2] + wsum[3];
#pragma unroll
        for (int e = 0; e < 8; e++) {
            int sidx = tid * 8 + e;
            int rk = base + pre[e]; // unmasked keys strictly before sidx
            // bijective: unmasked -> rank; masked -> nq + (masked before sidx)
            pos[b * SEQ + sidx] = m[e] ? rk : (nq + sidx - rk);
        }
        if (tid == 0) nkeys[b] = nq;
    }
}

// -------- gatherV: transpose compact V columns + zero K pad rows -------------
// Vtc[bh][d][j] = Vc[bh][j][d] for j<n, else 0. Also zeroes Kc rows [n, npad)
// (the only pad rows attn reads; attn needs them = 0 so p = 1 there).
__global__ __launch_bounds__(256) void gatherV(const unsigned short* __restrict__ Vc,
                                               const int* __restrict__ nkeys,
                                               unsigned short* __restrict__ Kc,
                                               unsigned short* __restrict__ Vtc) {
    __shared__ unsigned short Tl[64][72];
    int tid = threadIdx.x;
    int j0 = blockIdx.x * 64, bh = blockIdx.y, b = bh / H_;
    int n = nkeys[b];
    int npad = (n + 63) & ~63;
    int row = tid >> 2, cb = (tid & 3) * 16;
    int j = j0 + row;
    unsigned short v[16];
    if (j < n) { // sequential compact read (no indirection)
        const unsigned short* gv = Vc + ((size_t)bh * SEQ + j) * DK_ + cb;
        *(uint4*)&v[0] = *(const uint4*)gv;
        *(uint4*)&v[8] = *(const uint4*)(gv + 8);
    } else {
        uint4 z = {0u, 0u, 0u, 0u};
        *(uint4*)&v[0] = z;
        *(uint4*)&v[8] = z;
        if (j < npad) { // zero the K pad rows attn will read
            unsigned short* ok = Kc + ((size_t)bh * SEQ + j) * DK_ + cb;
            *(uint4*)ok = z;
            *(uint4*)(ok + 8) = z;
        }
    }
#pragma unroll
    for (int e = 0; e < 16; e++)
        Tl[cb + e][row] = v[e];
    __syncthreads();
    uint4 o0 = *(const uint4*)&Tl[row][cb];
    uint4 o1 = *(const uint4*)&Tl[row][cb + 8];
    unsigned short* out = Vtc + ((size_t)bh * DK_ + row) * SEQ + j0 + cb;
    *(uint4*)out = o0;
    *(uint4*)(out + 8) = o1;
}

// ------------- GEMM: C[m][n] = A[m][:] . Wt[n][:] + bias[n], TM x 128 --------
// 2-phase pipeline: LDS double-buffer; stage(t+1) issued BEFORE waiting on
// tile t (counted vmcnt = next tile's loads in flight); raw s_barrier.
// QKV epilogue: K/V rows land at pos[s] (compacted); Q rows at s.
template <int QKV, int TM>
__global__ __launch_bounds__(256) void gemm128(
    const unsigned short* __restrict__ A0, const unsigned short* __restrict__ A1,
    const unsigned short* __restrict__ A2, const unsigned short* __restrict__ Wt,
    const float* __restrict__ bias0, const float* __restrict__ bias1,
    const float* __restrict__ bias2,
    const int* __restrict__ pos,
    void* __restrict__ O0, void* __restrict__ O1, void* __restrict__ O2) {
    __shared__ unsigned short S[2][TM + 128][64]; // rows [0,TM)=A, [TM,TM+128)=B
    const int K = DM;
    const int NT = K / 64; // 12
    constexpr int NI = TM / 32; // acc row-frags per wave
    constexpr int AC = TM / 32; // A-stage instrs per wave
    int tid = threadIdx.x;
    int wave = tid >> 6, lane = tid & 63, quad = lane >> 4, l15 = lane & 15;
    int wr = wave >> 1, wc = wave & 1;

    // XCD-aware bijective swizzle (nwg % 8 == 0 for both grids)
    int nwg = gridDim.x * gridDim.y;
    int lin = blockIdx.y * gridDim.x + blockIdx.x;
    int swz = (lin & 7) * (nwg >> 3) + (lin >> 3);
    int bx = swz % gridDim.x, by = swz / gridDim.x;
    int m0 = bx * TM, n0 = by * 128;
    int lrow = lane >> 3, lcol = (lane & 7) * 8;

    int mi = 0, nb0 = n0;
    const unsigned short* A = A0;
    const float* bias = bias0;
    void* O = O0;
    if constexpr (QKV) {
        mi = n0 >= 1536 ? 2 : (n0 >= 768 ? 1 : 0);
        nb0 = n0 - mi * 768;
        A = mi == 0 ? A0 : (mi == 1 ? A1 : A2);
        bias = mi == 0 ? bias0 : (mi == 1 ? bias1 : bias2);
        O = mi == 0 ? O0 : (mi == 1 ? O1 : O2);
    }

    f32x4 acc[NI][4];
#pragma unroll
    for (int i = 0; i < NI; i++)
#pragma unroll
        for (int j = 0; j < 4; j++)
#pragma unroll
            for (int r = 0; r < 4; r++) acc[i][j][r] = 0.f;

    const unsigned short* gA = A + (size_t)(m0 + (TM / 4) * wave + lrow) * K + lcol;
    const unsigned short* gB = Wt + (size_t)(n0 + 32 * wave + lrow) * K + lcol;

    // prologue: stage tile 0 into buf 0
#pragma unroll
    for (int c = 0; c < AC; c++)
        gload_lds16(gA + (size_t)8 * c * K, &S[0][(TM / 4) * wave + 8 * c][0], lane);
#pragma unroll
    for (int c = 0; c < 4; c++)
        gload_lds16(gB + (size_t)8 * c * K, &S[0][TM + 32 * wave + 8 * c][0], lane);

    for (int t = 0; t < NT; t++) {
        int cur = t & 1;
        if (t + 1 < NT) { // issue next tile, then wait only for current tile
            int k0 = (t + 1) * 64;
#pragma unroll
            for (int c = 0; c < AC; c++)
                gload_lds16(gA + (size_t)8 * c * K + k0, &S[cur ^ 1][(TM / 4) * wave + 8 * c][0], lane);
#pragma unroll
            for (int c = 0; c < 4; c++)
                gload_lds16(gB + (size_t)8 * c * K + k0, &S[cur ^ 1][TM + 32 * wave + 8 * c][0], lane);
            if constexpr (TM == 128)
                asm volatile("s_waitcnt vmcnt(8)" ::: "memory");
            else
                asm volatile("s_waitcnt vmcnt(6)" ::: "memory");
        } else {
            asm volatile("s_waitcnt vmcnt(0)" ::: "memory");
        }
        __builtin_amdgcn_s_barrier(); // all waves' tile-t loads landed

        unsigned short (*Sl)[64] = S[cur];
#pragma unroll
        for (int ks = 0; ks < 64; ks += 32) {
            bf16x8 af[NI], bfr[4];
#pragma unroll
            for (int i = 0; i < NI; i++)
                af[i] = *(const bf16x8*)&Sl[(TM / 2) * wr + 16 * i + l15][ks + 8 * quad];
#pragma unroll
            for (int j = 0; j < 4; j++)
                bfr[j] = *(const bf16x8*)&Sl[TM + 64 * wc + 16 * j + l15][ks + 8 * quad];
#pragma unroll
            for (int i = 0; i < NI; i++)
#pragma unroll
                for (int j = 0; j < 4; j++)
                    acc[i][j] = __builtin_amdgcn_mfma_f32_16x16x32_bf16(af[i], bfr[j], acc[i][j], 0, 0, 0);
        }
        asm volatile("" ::: "memory");    // pin LDS reads above the barrier
        __builtin_amdgcn_s_barrier();     // safe to overwrite buf[cur] next iter
    }

    if constexpr (!QKV) {
#pragma unroll
        for (int j = 0; j < 4; j++) {
            int nn = nb0 + 64 * wc + 16 * j + l15;
            float bv = bias[nn];
#pragma unroll
            for (int i = 0; i < NI; i++)
#pragma unroll
                for (int r = 0; r < 4; r++) {
                    int m = m0 + (TM / 2) * wr + 16 * i + 4 * quad + r;
                    ((float*)O0)[(size_t)m * DM + nn] = acc[i][j][r] + bv;
                }
        }
    } else {
        float sc = mi == 0 ? QSCALE : 1.0f; // bake softmax scale+log2e into Q
        __syncthreads();
        unsigned short (*Cl)[128] = (unsigned short(*)[128])S; // 128x128, fits
#pragma unroll
        for (int j = 0; j < 4; j++) {
            float bv = bias[nb0 + 64 * wc + 16 * j + l15];
#pragma unroll
            for (int i = 0; i < NI; i++)
#pragma unroll
                for (int r = 0; r < 4; r++)
                    Cl[(TM / 2) * wr + 16 * i + 4 * quad + r][64 * wc + 16 * j + l15] =
                        f2bf((acc[i][j][r] + bv) * sc);
        }
        __syncthreads();
        int row = tid >> 1, half = tid & 1; // QKV is TM=128 only (proven path)
        int m = m0 + row;
        int b = m >> 11, s = m & 2047;
        int j = (mi == 0) ? s : pos[b * SEQ + s]; // K/V land compacted
        int h = (nb0 + 64 * half) >> 6;
        unsigned short* og = (unsigned short*)O + ((size_t)(b * H_ + h) * SEQ + j) * DK_;
        const unsigned short* cr = &Cl[row][64 * half];
#pragma unroll
        for (int c = 0; c < 4; c++)
            *(uint4*)(og + 16 * c) = *(const uint4*)(cr + 16 * c);
#pragma unroll
        for (int c = 0; c < 4; c++)
            *(uint4*)(og + 16 * c + 8) = *(const uint4*)(cr + 16 * c + 8);
    }
}

// ---------------- flash attention over COMPACTED keys, 2x2 wave split ---------
// Denominator via ones-vector MFMA: lsum[r] = sum_k p[q=qrl(r,hi)][k], same C/D
// row layout as o — no cross-lane shuffles; num/denom use identical bf16 p.
// R18 body (= R8): no setprio, no bh-remap (both measured harmful in R17).
__global__ __launch_bounds__(256) void attn_fa(const unsigned short* __restrict__ Q,
                                               const unsigned short* __restrict__ Kc,
                                               const unsigned short* __restrict__ Vtc,
                                               const int* __restrict__ nkeys,
                                               unsigned short* __restrict__ ctx) {
    __shared__ __align__(16) unsigned short Ql[64][72];
    __shared__ __align__(16) unsigned short Kl[64][72];
    __shared__ __align__(16) unsigned short Vl[64][68];
    __shared__ __align__(16) float Op[2][32][32]; // epilogue partials, per d-half
    __shared__ __align__(16) float lp[2][32];     // kh=1 partial row sums
    int tid = threadIdx.x;
    int wave = tid >> 6, lane = tid & 63;
    int l31 = lane & 31, hi = lane >> 5;
    int qh = wave & 1, kh = wave >> 1; // q-half, key-half
    int bh = blockIdx.y, b = bh / H_, h = bh % H_;
    int q0 = blockIdx.x * 64;

    int n = nkeys[b];
    int nt = (n + 63) >> 6;            // compacted key tiles
    float padf = (float)(nt * 64 - n); // zero-pad rows contribute p=1 each

    { // stage Q tile (64x64) once
        int row = tid >> 2, cb = (tid & 3) * 16;
        const unsigned short* gq = Q + ((size_t)bh * SEQ + q0 + row) * DK_ + cb;
        *(uint4*)&Ql[row][cb]     = *(const uint4*)gq;
        *(uint4*)&Ql[row][cb + 8] = *(const uint4*)(gq + 8);
    }
    __syncthreads(); // Ql staged

    // loop-invariant Q fragments (queries 32*qh + l31)
    bf16x8 qf[4];
#pragma unroll
    for (int c = 0; c < 4; c++)
        qf[c] = *(const bf16x8*)&Ql[32 * qh + l31][16 * c + 8 * hi];

    union { unsigned u[2]; bf16x4 v; } onesu;
    onesu.u[0] = 0x3F803F80u; onesu.u[1] = 0x3F803F80u; // bf16 1.0 x4
    bf16x4 ones = onesu.v;

    f32x16 o[2][2]; // [d-half][ilp]
    f32x16 lsum;    // row sums of p (denominator), same row layout as o
#pragma unroll
    for (int r = 0; r < 16; r++) lsum[r] = 0.f;
#pragma unroll
    for (int dt = 0; dt < 2; dt++)
#pragma unroll
        for (int p = 0; p < 2; p++)
#pragma unroll
            for (int r = 0; r < 16; r++) o[dt][p][r] = 0.f;

    int krow = tid >> 2, kcb = (tid & 3) * 16;
    const unsigned short* gk = Kc + ((size_t)bh * SEQ + krow) * DK_ + kcb;
    const unsigned short* gv = Vtc + ((size_t)bh * DK_ + krow) * SEQ + kcb;

    // prefetch iter 0
    uint4 kr0 = *(const uint4*)gk, kr1 = *(const uint4*)(gk + 8);
    uint4 vr0 = *(const uint4*)gv, vr1 = *(const uint4*)(gv + 8);

    for (int kt = 0; kt < nt; kt++) {
        __syncthreads(); // prev iter's K/V LDS reads done
        *(uint4*)&Kl[krow][kcb]     = kr0;
        *(uint4*)&Kl[krow][kcb + 8] = kr1;
        *(uint4*)&Vl[krow][kcb]     = vr0;
        *(uint4*)&Vl[krow][kcb + 8] = vr1;
        __syncthreads(); // tiles visible
        if (kt + 1 < nt) { // prefetch next (latency hidden under compute)
            gk += (size_t)64 * DK_;
            gv += 64;
            kr0 = *(const uint4*)gk; kr1 = *(const uint4*)(gk + 8);
            vr0 = *(const uint4*)gv; vr1 = *(const uint4*)(gv + 8);
        }

        // S^T = K.Q^T (32 keys x 32 queries for this wave); zero C-init, no mask
        f32x16 sT;
#pragma unroll
        for (int r = 0; r < 16; r++) sT[r] = 0.f;
#pragma unroll
        for (int c = 0; c < 4; c++) {
            bf16x8 kf = *(const bf16x8*)&Kl[32 * kh + l31][16 * c + 8 * hi];
            sT = __builtin_amdgcn_mfma_f32_32x32x16_bf16(kf, qf[c], sT, 0, 0, 0);
        }

        // p = 2^s (scale pre-baked into Q): regs ARE the PV MFMA A-operand
        bf16x4 pfrag[4];
#pragma unroll
        for (int c = 0; c < 4; c++) {
            float p0 = exp2fast(sT[4 * c + 0]);
            float p1 = exp2fast(sT[4 * c + 1]);
            float p2 = exp2fast(sT[4 * c + 2]);
            float p3 = exp2fast(sT[4 * c + 3]);
            union { unsigned u[2]; bf16x4 v; } pk;
            pk.u[0] = pack2bf(p0, p1);
            pk.u[1] = pack2bf(p2, p3);
            pfrag[c] = pk.v;
        }

        // denominator row sums on the MFMA pipe (B = ones)
#pragma unroll
        for (int c = 0; c < 4; c++)
            lsum = mfma32x8(pfrag[c], ones, lsum);

        // O[q][d] += P.V over this wave's 32 keys
#pragma unroll
        for (int dt = 0; dt < 2; dt++)
#pragma unroll
            for (int c = 0; c < 4; c++) {
                bf16x4 vf = *(const bf16x4*)&Vl[32 * dt + l31][32 * kh + 8 * c + 4 * hi];
                o[dt][c & 1] = mfma32x8(pfrag[c], vf, o[dt][c & 1]);
            }
    }

    // combine across key-half wave pairs (two d-half chunks through Op), store
#pragma unroll
    for (int dt = 0; dt < 2; dt++) {
        if (kh == 1) {
#pragma unroll
            for (int r = 0; r < 16; r++) {
                int qrl = (r & 3) + 8 * (r >> 2) + 4 * hi;
                Op[qh][qrl][l31] = o[dt][0][r] + o[dt][1][r];
                if (dt == 0 && l31 == 0) lp[qh][qrl] = lsum[r];
            }
        }
        __syncthreads();
        if (kh == 0) {
#pragma unroll
            for (int r = 0; r < 16; r++) {
                int qrl = (r & 3) + 8 * (r >> 2) + 4 * hi;
                float l = lsum[r] + lp[qh][qrl] - padf; // remove pad-row p=1 terms
                float iv = l > 0.f ? 1.f / l : 0.f;
                int qg = q0 + 32 * qh + qrl;
                size_t base = ((size_t)b * SEQ + qg) * DM + h * DK_;
                float v = o[dt][0][r] + o[dt][1][r] + Op[qh][qrl][l31];
                ctx[base + 32 * dt + l31] = f2bf(v * iv);
            }
        }
        __syncthreads(); // Op safe for next chunk
    }
}

extern "C" void kernel_launch(void* const* d_in, const int* in_sizes, int n_in,
                              void* d_out, int out_size, void* d_ws, size_t ws_size,
                              hipStream_t stream) {
    const float* q  = (const float*)d_in[0];
    const float* k  = (const float*)d_in[1];
    const float* v  = (const float*)d_in[2];
    const float* Wq = (const float*)d_in[3];
    const float* bq = (const float*)d_in[4];
    const float* Wk = (const float*)d_in[5];
    const float* bk = (const float*)d_in[6];
    const float* Wv = (const float*)d_in[7];
    const float* bv = (const float*)d_in[8];
    const float* Wo = (const float*)d_in[9];
    const float* bo = (const float*)d_in[10];
    const int* mask = (const int*)d_in[11];

    unsigned short* ws = (unsigned short*)d_ws;
    unsigned short* qb = ws;
    unsigned short* kb = ws + PER_IN;
    unsigned short* vb = ws + 2 * PER_IN;
    unsigned short* Qh = ws + 3 * PER_IN;
    unsigned short* Kc = ws + 4 * PER_IN;  // K written COMPACTED by QKV GEMM
    unsigned short* Vc = ws + 5 * PER_IN;  // V written COMPACTED by QKV GEMM
    unsigned short* WtQKV = ws + 6 * PER_IN;
    unsigned short* WtO = WtQKV + (size_t)3 * DM * DM;
    unsigned short* Vtc = vb;  // vb dead after QKV GEMM
    unsigned short* ctx = qb;  // qb dead after QKV GEMM
    int* pos = (int*)d_out;    // dead until final GEMM overwrites d_out
    int* nk = pos + B_DIM * SEQ;

    // prep: 4608 cvt blocks + 2304 transpose blocks + 2 scan blocks
    prep<<<dim3(6914), 256, 0, stream>>>(q, k, v, qb, kb, vb,
                                         Wq, Wk, Wv, Wo, WtQKV, mask, pos, nk);

    gemm128<1, 128><<<dim3(MROWS / 128, 3 * DM / 128), 256, 0, stream>>>(
        qb, kb, vb, WtQKV, bq, bk, bv, pos, Qh, Kc, Vc);

    gatherV<<<dim3(SEQ / 64, B_DIM * H_), 256, 0, stream>>>(Vc, nk, Kc, Vtc);

    attn_fa<<<dim3(SEQ / 64, B_DIM * H_), 256, 0, stream>>>(Qh, Kc, Vtc, nk, ctx);

    gemm128<0, 64><<<dim3(MROWS / 64, DM / 128), 256, 0, stream>>>(
        ctx, ctx, ctx, WtO, bo, bo, bo, pos, d_out, d_out, d_out);
}

// Round 13
// 189.535 us; speedup vs baseline: 1.0573x; 1.0303x over previous
//
#include <hip/hip_runtime.h>

// Multi-head attention, B=2 S=2048 D=768 H=12 DK=64. I/O fp32, internal bf16 MFMA.
// Round 20: T2 XOR-swizzle on gemm128 LDS staging/reads (single change).
//   R2 counters: SQ_LDS_BANK_CONFLICT = 6.12M/dispatch on gemm128. Cause: LDS
//   rows are 128B = exact bank wrap, so fragment ds_read_b128 banks depend only
//   on (ks,quad) -> 16 same-quad lanes share 4 banks (16-way). Fix per rule 21
//   (both-sides-or-neither with global_load_lds): permute the GLOBAL source col
//   per lane (lcol = ((lane&7)^(lane>>3))*8; LDS write stays linear) and apply
//   the SAME involution on reads (col16 = ((ks>>3)+quad) ^ (row&7); row&7 =
//   l15&7 at every read site, all row bases are 0 mod 8). Element-tracked by
//   hand (lanes 13, 27). After: col16 spans 8 slots -> all 32 banks, 2-way=free.
//   Also a clean test of the T2 2-phase regime gate in a LATENCY-bound GEMM
//   (2 blocks/CU; catalog's null was throughput-bound).
// R19: K/V written compacted by QKV epilogue via pos[] (bijective); gatherV =
// sequential V transpose + K pad-row zeroing. R18/R17: no setprio/bh-swizzle on
// attn (measured harmful); attn is NOT memory-bound. R16: fill dispatches =
// constant-work clock probe; normalize cross-round walls. R15: no VGPR-capping
// launch_bounds on attn. R10: GEMM 2-phase pipeline (dbuf LDS + counted vmcnt +
// raw s_barrier). R9: mask compaction; no mask path in attn (zero pads -> p=1,
// corrected in denominator); Q pre-scaled 0.125*log2(e) -> raw v_exp_f32.
// Replay-hardening: pos/nk scratch in d_out; no early return before barriers;
// no inline-asm transcendentals. attn LDS strides 72/68 proven conflict-free.

#define H_ 12
#define DK_ 64
#define B_DIM 2
#define SEQ 2048
#define DM 768
#define MROWS 4096
#define PER_IN ((size_t)MROWS * DM)
#define QSCALE 0.18033688011112042f

typedef short bf16x8 __attribute__((ext_vector_type(8)));
typedef short bf16x4 __attribute__((ext_vector_type(4)));
typedef float f32x4 __attribute__((ext_vector_type(4)));
typedef float f32x16 __attribute__((ext_vector_type(16)));

__device__ inline unsigned short f2bf(float f) {
    union { float f; unsigned int i; } x; x.f = f;
    unsigned int r = x.i + 0x7fff + ((x.i >> 16) & 1); // RNE
    return (unsigned short)(r >> 16);
}

__device__ inline unsigned pack2bf(float lo, float hi) {
#if __has_builtin(__builtin_amdgcn_cvt_pk_bf16_f32)
    auto v = __builtin_amdgcn_cvt_pk_bf16_f32(lo, hi);
    return __builtin_bit_cast(unsigned, v);
#else
    return (unsigned)f2bf(lo) | ((unsigned)f2bf(hi) << 16);
#endif
}

__device__ inline float exp2fast(float x) { // 2^x
#if __has_builtin(__builtin_amdgcn_exp2f)
    return __builtin_amdgcn_exp2f(x);
#else
    return exp2f(x);
#endif
}

__device__ inline f32x16 mfma32x8(bf16x4 a, bf16x4 b, f32x16 c) {
#if __has_builtin(__builtin_amdgcn_mfma_f32_32x32x8bf16_1k)
    return __builtin_amdgcn_mfma_f32_32x32x8bf16_1k(a, b, c, 0, 0, 0);
#else
    asm("v_mfma_f32_32x32x8_bf16 %0, %1, %2, %0" : "+v"(c) : "v"(a), "v"(b));
    return c;
#endif
}

// async 16B/lane global->LDS; ldsbase must be wave-uniform (HW adds lane*16B)
__device__ inline void gload_lds16(const unsigned short* g, unsigned short* ldsbase,
                                   int lane) {
#if __has_builtin(__builtin_amdgcn_global_load_lds)
    __builtin_amdgcn_global_load_lds(
        (const __attribute__((address_space(1))) unsigned int*)g,
        (__attribute__((address_space(3))) unsigned int*)ldsbase, 16, 0, 0);
#else
    *(uint4*)(ldsbase + 8 * lane) = *(const uint4*)g;
#endif
}

// -------- prep: fp32->bf16 convert x3 (8 f/thr)  |  4 transposes  |  scan -----
// Flat 1D grid: [0,4608) cvt; [4608,6912) transpose; [6912,6914) maskscan.
// maskscan emits pos[s]: bijective compact map (unmasked->rank, masked->n+mrank).
__global__ __launch_bounds__(256) void prep(
    const float* __restrict__ q, const float* __restrict__ k,
    const float* __restrict__ v,
    unsigned short* __restrict__ qb, unsigned short* __restrict__ kb,
    unsigned short* __restrict__ vb,
    const float* __restrict__ w0, const float* __restrict__ w1,
    const float* __restrict__ w2, const float* __restrict__ w3,
    unsigned short* __restrict__ wtbase,
    const int* __restrict__ mask, int* __restrict__ pos,
    int* __restrict__ nkeys) {
    __shared__ unsigned short t[32][33];
    __shared__ int wsum[4];
    int job = blockIdx.x, tid = threadIdx.x;
    if (job < 4608) { // ---- convert, 8 floats / thread ----
        int buf = job / 1536, x = job % 1536;
        const float* src = buf == 0 ? q : (buf == 1 ? k : v);
        unsigned short* dst = buf == 0 ? qb : (buf == 1 ? kb : vb);
        size_t i = ((size_t)x * 256 + tid) * 8;
        float4 f0 = *(const float4*)(src + i);
        float4 f1 = *(const float4*)(src + i + 4);
        ushort4 u0, u1;
        u0.x = f2bf(f0.x); u0.y = f2bf(f0.y); u0.z = f2bf(f0.z); u0.w = f2bf(f0.w);
        u1.x = f2bf(f1.x); u1.y = f2bf(f1.y); u1.z = f2bf(f1.z); u1.w = f2bf(f1.w);
        *(ushort4*)(dst + i) = u0;
        *(ushort4*)(dst + i + 4) = u1;
    } else if (job < 6912) { // ---- weight transpose Wt[n][k] = bf16(W[k][n]) --
        int tb = job - 4608;
        int z = tb / 576, r = tb % 576, by = r / 24, bx = r % 24;
        const float* in = z == 0 ? w0 : (z == 1 ? w1 : (z == 2 ? w2 : w3));
        unsigned short* out = wtbase + (size_t)z * DM * DM;
        int x = tid & 31, y = tid >> 5; // 32 x 8
        int k0 = bx * 32, n0 = by * 32;
#pragma unroll
        for (int i = 0; i < 32; i += 8)
            t[y + i][x] = f2bf(in[(size_t)(k0 + y + i) * DM + n0 + x]);
        __syncthreads();
#pragma unroll
        for (int i = 0; i < 32; i += 8)
            out[(size_t)(n0 + y + i) * DM + k0 + x] = t[x][y + i];
    } else { // ---- mask scan: inverse-rank compact map ----
        int b = job - 6912;
        int lane = tid & 63, wave = tid >> 6;
        const int* mp = mask + (size_t)b * SEQ + tid * 8;
        int4 a = *(const int4*)mp;
        int4 c = *(const int4*)(mp + 4);
        int m[8] = {a.x, a.y, a.z, a.w, c.x, c.y, c.z, c.w};
        int pre[8], s = 0;
#pragma unroll
        for (int e = 0; e < 8; e++) { pre[e] = s; s += (m[e] != 0); }
        int incl = s;
#pragma unroll
        for (int off = 1; off < 64; off <<= 1) {
            int vv = __shfl_up(incl, off);
            if (lane >= off) incl += vv;
        }
        int lexcl = incl - s;
        if (lane == 63) wsum[wave] = incl;
        __syncthreads();
        int base = lexcl;
        for (int w = 0; w < wave; w++) base += wsum[w];
        int nq = wsum[0] + wsum[1] + wsum[2] + wsum[3];
#pragma unroll
        for (int e = 0; e < 8; e++) {
            int sidx = tid * 8 + e;
            int rk = base + pre[e]; // unmasked keys strictly before sidx
            // bijective: unmasked -> rank; masked -> nq + (masked before sidx)
            pos[b * SEQ + sidx] = m[e] ? rk : (nq + sidx - rk);
        }
        if (tid == 0) nkeys[b] = nq;
    }
}

// -------- gatherV: transpose compact V columns + zero K pad rows -------------
// Vtc[bh][d][j] = Vc[bh][j][d] for j<n, else 0. Also zeroes Kc rows [n, npad)
// (the only pad rows attn reads; attn needs them = 0 so p = 1 there).
__global__ __launch_bounds__(256) void gatherV(const unsigned short* __restrict__ Vc,
                                               const int* __restrict__ nkeys,
                                               unsigned short* __restrict__ Kc,
                                               unsigned short* __restrict__ Vtc) {
    __shared__ unsigned short Tl[64][72];
    int tid = threadIdx.x;
    int j0 = blockIdx.x * 64, bh = blockIdx.y, b = bh / H_;
    int n = nkeys[b];
    int npad = (n + 63) & ~63;
    int row = tid >> 2, cb = (tid & 3) * 16;
    int j = j0 + row;
    unsigned short v[16];
    if (j < n) { // sequential compact read (no indirection)
        const unsigned short* gv = Vc + ((size_t)bh * SEQ + j) * DK_ + cb;
        *(uint4*)&v[0] = *(const uint4*)gv;
        *(uint4*)&v[8] = *(const uint4*)(gv + 8);
    } else {
        uint4 z = {0u, 0u, 0u, 0u};
        *(uint4*)&v[0] = z;
        *(uint4*)&v[8] = z;
        if (j < npad) { // zero the K pad rows attn will read
            unsigned short* ok = Kc + ((size_t)bh * SEQ + j) * DK_ + cb;
            *(uint4*)ok = z;
            *(uint4*)(ok + 8) = z;
        }
    }
#pragma unroll
    for (int e = 0; e < 16; e++)
        Tl[cb + e][row] = v[e];
    __syncthreads();
    uint4 o0 = *(const uint4*)&Tl[row][cb];
    uint4 o1 = *(const uint4*)&Tl[row][cb + 8];
    unsigned short* out = Vtc + ((size_t)bh * DK_ + row) * SEQ + j0 + cb;
    *(uint4*)out = o0;
    *(uint4*)(out + 8) = o1;
}

// ------------- GEMM: C[m][n] = A[m][:] . Wt[n][:] + bias[n], TM x 128 --------
// 2-phase pipeline: LDS double-buffer; stage(t+1) issued BEFORE waiting on
// tile t (counted vmcnt = next tile's loads in flight); raw s_barrier.
// T2 XOR swizzle (rule 21 both-sides): LDS write stays LINEAR (gload_lds16);
// the SOURCE col is permuted per lane (lcol XOR lane>>3) and reads apply the
// same involution: col16 = ((ks>>3)+quad) ^ (row&7), row&7 == l15&7 everywhere.
template <int QKV, int TM>
__global__ __launch_bounds__(256) void gemm128(
    const unsigned short* __restrict__ A0, const unsigned short* __restrict__ A1,
    const unsigned short* __restrict__ A2, const unsigned short* __restrict__ Wt,
    const float* __restrict__ bias0, const float* __restrict__ bias1,
    const float* __restrict__ bias2,
    const int* __restrict__ pos,
    void* __restrict__ O0, void* __restrict__ O1, void* __restrict__ O2) {
    __shared__ unsigned short S[2][TM + 128][64]; // rows [0,TM)=A, [TM,TM+128)=B
    const int K = DM;
    const int NT = K / 64; // 12
    constexpr int NI = TM / 32; // acc row-frags per wave
    constexpr int AC = TM / 32; // A-stage instrs per wave
    int tid = threadIdx.x;
    int wave = tid >> 6, lane = tid & 63, quad = lane >> 4, l15 = lane & 15;
    int wr = wave >> 1, wc = wave & 1;

    // XCD-aware bijective swizzle (nwg % 8 == 0 for both grids)
    int nwg = gridDim.x * gridDim.y;
    int lin = blockIdx.y * gridDim.x + blockIdx.x;
    int swz = (lin & 7) * (nwg >> 3) + (lin >> 3);
    int bx = swz % gridDim.x, by = swz / gridDim.x;
    int m0 = bx * TM, n0 = by * 128;
    int lrow = lane >> 3;
    // T2 source swizzle: lane's 16B slot receives global col16 ^ (row&7)
    int lcol = (((lane & 7) ^ lrow) & 7) * 8;

    int mi = 0, nb0 = n0;
    const unsigned short* A = A0;
    const float* bias = bias0;
    void* O = O0;
    if constexpr (QKV) {
        mi = n0 >= 1536 ? 2 : (n0 >= 768 ? 1 : 0);
        nb0 = n0 - mi * 768;
        A = mi == 0 ? A0 : (mi == 1 ? A1 : A2);
        bias = mi == 0 ? bias0 : (mi == 1 ? bias1 : bias2);
        O = mi == 0 ? O0 : (mi == 1 ? O1 : O2);
    }

    f32x4 acc[NI][4];
#pragma unroll
    for (int i = 0; i < NI; i++)
#pragma unroll
        for (int j = 0; j < 4; j++)
#pragma unroll
            for (int r = 0; r < 4; r++) acc[i][j][r] = 0.f;

    const unsigned short* gA = A + (size_t)(m0 + (TM / 4) * wave + lrow) * K + lcol;
    const unsigned short* gB = Wt + (size_t)(n0 + 32 * wave + lrow) * K + lcol;

    // prologue: stage tile 0 into buf 0
#pragma unroll
    for (int c = 0; c < AC; c++)
        gload_lds16(gA + (size_t)8 * c * K, &S[0][(TM / 4) * wave + 8 * c][0], lane);
#pragma unroll
    for (int c = 0; c < 4; c++)
        gload_lds16(gB + (size_t)8 * c * K, &S[0][TM + 32 * wave + 8 * c][0], lane);

    for (int t = 0; t < NT; t++) {
        int cur = t & 1;
        if (t + 1 < NT) { // issue next tile, then wait only for current tile
            int k0 = (t + 1) * 64;
#pragma unroll
            for (int c = 0; c < AC; c++)
                gload_lds16(gA + (size_t)8 * c * K + k0, &S[cur ^ 1][(TM / 4) * wave + 8 * c][0], lane);
#pragma unroll
            for (int c = 0; c < 4; c++)
                gload_lds16(gB + (size_t)8 * c * K + k0, &S[cur ^ 1][TM + 32 * wave + 8 * c][0], lane);
            if constexpr (TM == 128)
                asm volatile("s_waitcnt vmcnt(8)" ::: "memory");
            else
                asm volatile("s_waitcnt vmcnt(6)" ::: "memory");
        } else {
            asm volatile("s_waitcnt vmcnt(0)" ::: "memory");
        }
        __builtin_amdgcn_s_barrier(); // all waves' tile-t loads landed

        unsigned short (*Sl)[64] = S[cur];
        int rx = l15 & 7; // row&7 for all fragment rows (bases are 0 mod 8)
#pragma unroll
        for (int ks = 0; ks < 64; ks += 32) {
            bf16x8 af[NI], bfr[4];
#pragma unroll
            for (int i = 0; i < NI; i++)
                af[i] = *(const bf16x8*)&Sl[(TM / 2) * wr + 16 * i + l15]
                                           [((((ks >> 3) + quad) ^ rx) & 7) * 8];
#pragma unroll
            for (int j = 0; j < 4; j++)
                bfr[j] = *(const bf16x8*)&Sl[TM + 64 * wc + 16 * j + l15]
                                            [((((ks >> 3) + quad) ^ rx) & 7) * 8];
#pragma unroll
            for (int i = 0; i < NI; i++)
#pragma unroll
                for (int j = 0; j < 4; j++)
                    acc[i][j] = __builtin_amdgcn_mfma_f32_16x16x32_bf16(af[i], bfr[j], acc[i][j], 0, 0, 0);
        }
        asm volatile("" ::: "memory");    // pin LDS reads above the barrier
        __builtin_amdgcn_s_barrier();     // safe to overwrite buf[cur] next iter
    }

    if constexpr (!QKV) {
#pragma unroll
        for (int j = 0; j < 4; j++) {
            int nn = nb0 + 64 * wc + 16 * j + l15;
            float bv = bias[nn];
#pragma unroll
            for (int i = 0; i < NI; i++)
#pragma unroll
                for (int r = 0; r < 4; r++) {
                    int m = m0 + (TM / 2) * wr + 16 * i + 4 * quad + r;
                    ((float*)O0)[(size_t)m * DM + nn] = acc[i][j][r] + bv;
                }
        }
    } else {
        float sc = mi == 0 ? QSCALE : 1.0f; // bake softmax scale+log2e into Q
        __syncthreads();
        unsigned short (*Cl)[128] = (unsigned short(*)[128])S; // 128x128, fits
#pragma unroll
        for (int j = 0; j < 4; j++) {
            float bv = bias[nb0 + 64 * wc + 16 * j + l15];
#pragma unroll
            for (int i = 0; i < NI; i++)
#pragma unroll
                for (int r = 0; r < 4; r++)
                    Cl[(TM / 2) * wr + 16 * i + 4 * quad + r][64 * wc + 16 * j + l15] =
                        f2bf((acc[i][j][r] + bv) * sc);
        }
        __syncthreads();
        int row = tid >> 1, half = tid & 1; // QKV is TM=128 only (proven path)
        int m = m0 + row;
        int b = m >> 11, s = m & 2047;
        int j = (mi == 0) ? s : pos[b * SEQ + s]; // K/V land compacted
        int h = (nb0 + 64 * half) >> 6;
        unsigned short* og = (unsigned short*)O + ((size_t)(b * H_ + h) * SEQ + j) * DK_;
        const unsigned short* cr = &Cl[row][64 * half];
#pragma unroll
        for (int c = 0; c < 4; c++)
            *(uint4*)(og + 16 * c) = *(const uint4*)(cr + 16 * c);
#pragma unroll
        for (int c = 0; c < 4; c++)
            *(uint4*)(og + 16 * c + 8) = *(const uint4*)(cr + 16 * c + 8);
    }
}

// ---------------- flash attention over COMPACTED keys, 2x2 wave split ---------
// Denominator via ones-vector MFMA: lsum[r] = sum_k p[q=qrl(r,hi)][k], same C/D
// row layout as o — no cross-lane shuffles; num/denom use identical bf16 p.
// R18 body (= R8): no setprio, no bh-remap (both measured harmful in R17).
__global__ __launch_bounds__(256) void attn_fa(const unsigned short* __restrict__ Q,
                                               const unsigned short* __restrict__ Kc,
                                               const unsigned short* __restrict__ Vtc,
                                               const int* __restrict__ nkeys,
                                               unsigned short* __restrict__ ctx) {
    __shared__ __align__(16) unsigned short Ql[64][72];
    __shared__ __align__(16) unsigned short Kl[64][72];
    __shared__ __align__(16) unsigned short Vl[64][68];
    __shared__ __align__(16) float Op[2][32][32]; // epilogue partials, per d-half
    __shared__ __align__(16) float lp[2][32];     // kh=1 partial row sums
    int tid = threadIdx.x;
    int wave = tid >> 6, lane = tid & 63;
    int l31 = lane & 31, hi = lane >> 5;
    int qh = wave & 1, kh = wave >> 1; // q-half, key-half
    int bh = blockIdx.y, b = bh / H_, h = bh % H_;
    int q0 = blockIdx.x * 64;

    int n = nkeys[b];
    int nt = (n + 63) >> 6;            // compacted key tiles
    float padf = (float)(nt * 64 - n); // zero-pad rows contribute p=1 each

    { // stage Q tile (64x64) once
        int row = tid >> 2, cb = (tid & 3) * 16;
        const unsigned short* gq = Q + ((size_t)bh * SEQ + q0 + row) * DK_ + cb;
        *(uint4*)&Ql[row][cb]     = *(const uint4*)gq;
        *(uint4*)&Ql[row][cb + 8] = *(const uint4*)(gq + 8);
    }
    __syncthreads(); // Ql staged

    // loop-invariant Q fragments (queries 32*qh + l31)
    bf16x8 qf[4];
#pragma unroll
    for (int c = 0; c < 4; c++)
        qf[c] = *(const bf16x8*)&Ql[32 * qh + l31][16 * c + 8 * hi];

    union { unsigned u[2]; bf16x4 v; } onesu;
    onesu.u[0] = 0x3F803F80u; onesu.u[1] = 0x3F803F80u; // bf16 1.0 x4
    bf16x4 ones = onesu.v;

    f32x16 o[2][2]; // [d-half][ilp]
    f32x16 lsum;    // row sums of p (denominator), same row layout as o
#pragma unroll
    for (int r = 0; r < 16; r++) lsum[r] = 0.f;
#pragma unroll
    for (int dt = 0; dt < 2; dt++)
#pragma unroll
        for (int p = 0; p < 2; p++)
#pragma unroll
            for (int r = 0; r < 16; r++) o[dt][p][r] = 0.f;

    int krow = tid >> 2, kcb = (tid & 3) * 16;
    const unsigned short* gk = Kc + ((size_t)bh * SEQ + krow) * DK_ + kcb;
    const unsigned short* gv = Vtc + ((size_t)bh * DK_ + krow) * SEQ + kcb;

    // prefetch iter 0
    uint4 kr0 = *(const uint4*)gk, kr1 = *(const uint4*)(gk + 8);
    uint4 vr0 = *(const uint4*)gv, vr1 = *(const uint4*)(gv + 8);

    for (int kt = 0; kt < nt; kt++) {
        __syncthreads(); // prev iter's K/V LDS reads done
        *(uint4*)&Kl[krow][kcb]     = kr0;
        *(uint4*)&Kl[krow][kcb + 8] = kr1;
        *(uint4*)&Vl[krow][kcb]     = vr0;
        *(uint4*)&Vl[krow][kcb + 8] = vr1;
        __syncthreads(); // tiles visible
        if (kt + 1 < nt) { // prefetch next (latency hidden under compute)
            gk += (size_t)64 * DK_;
            gv += 64;
            kr0 = *(const uint4*)gk; kr1 = *(const uint4*)(gk + 8);
            vr0 = *(const uint4*)gv; vr1 = *(const uint4*)(gv + 8);
        }

        // S^T = K.Q^T (32 keys x 32 queries for this wave); zero C-init, no mask
        f32x16 sT;
#pragma unroll
        for (int r = 0; r < 16; r++) sT[r] = 0.f;
#pragma unroll
        for (int c = 0; c < 4; c++) {
            bf16x8 kf = *(const bf16x8*)&Kl[32 * kh + l31][16 * c + 8 * hi];
            sT = __builtin_amdgcn_mfma_f32_32x32x16_bf16(kf, qf[c], sT, 0, 0, 0);
        }

        // p = 2^s (scale pre-baked into Q): regs ARE the PV MFMA A-operand
        bf16x4 pfrag[4];
#pragma unroll
        for (int c = 0; c < 4; c++) {
            float p0 = exp2fast(sT[4 * c + 0]);
            float p1 = exp2fast(sT[4 * c + 1]);
            float p2 = exp2fast(sT[4 * c + 2]);
            float p3 = exp2fast(sT[4 * c + 3]);
            union { unsigned u[2]; bf16x4 v; } pk;
            pk.u[0] = pack2bf(p0, p1);
            pk.u[1] = pack2bf(p2, p3);
            pfrag[c] = pk.v;
        }

        // denominator row sums on the MFMA pipe (B = ones)
#pragma unroll
        for (int c = 0; c < 4; c++)
            lsum = mfma32x8(pfrag[c], ones, lsum);

        // O[q][d] += P.V over this wave's 32 keys
#pragma unroll
        for (int dt = 0; dt < 2; dt++)
#pragma unroll
            for (int c = 0; c < 4; c++) {
                bf16x4 vf = *(const bf16x4*)&Vl[32 * dt + l31][32 * kh + 8 * c + 4 * hi];
                o[dt][c & 1] = mfma32x8(pfrag[c], vf, o[dt][c & 1]);
            }
    }

    // combine across key-half wave pairs (two d-half chunks through Op), store
#pragma unroll
    for (int dt = 0; dt < 2; dt++) {
        if (kh == 1) {
#pragma unroll
            for (int r = 0; r < 16; r++) {
                int qrl = (r & 3) + 8 * (r >> 2) + 4 * hi;
                Op[qh][qrl][l31] = o[dt][0][r] + o[dt][1][r];
                if (dt == 0 && l31 == 0) lp[qh][qrl] = lsum[r];
            }
        }
        __syncthreads();
        if (kh == 0) {
#pragma unroll
            for (int r = 0; r < 16; r++) {
                int qrl = (r & 3) + 8 * (r >> 2) + 4 * hi;
                float l = lsum[r] + lp[qh][qrl] - padf; // remove pad-row p=1 terms
                float iv = l > 0.f ? 1.f / l : 0.f;
                int qg = q0 + 32 * qh + qrl;
                size_t base = ((size_t)b * SEQ + qg) * DM + h * DK_;
                float v = o[dt][0][r] + o[dt][1][r] + Op[qh][qrl][l31];
                ctx[base + 32 * dt + l31] = f2bf(v * iv);
            }
        }
        __syncthreads(); // Op safe for next chunk
    }
}

extern "C" void kernel_launch(void* const* d_in, const int* in_sizes, int n_in,
                              void* d_out, int out_size, void* d_ws, size_t ws_size,
                              hipStream_t stream) {
    const float* q  = (const float*)d_in[0];
    const float* k  = (const float*)d_in[1];
    const float* v  = (const float*)d_in[2];
    const float* Wq = (const float*)d_in[3];
    const float* bq = (const float*)d_in[4];
    const float* Wk = (const float*)d_in[5];
    const float* bk = (const float*)d_in[6];
    const float* Wv = (const float*)d_in[7];
    const float* bv = (const float*)d_in[8];
    const float* Wo = (const float*)d_in[9];
    const float* bo = (const float*)d_in[10];
    const int* mask = (const int*)d_in[11];

    unsigned short* ws = (unsigned short*)d_ws;
    unsigned short* qb = ws;
    unsigned short* kb = ws + PER_IN;
    unsigned short* vb = ws + 2 * PER_IN;
    unsigned short* Qh = ws + 3 * PER_IN;
    unsigned short* Kc = ws + 4 * PER_IN;  // K written COMPACTED by QKV GEMM
    unsigned short* Vc = ws + 5 * PER_IN;  // V written COMPACTED by QKV GEMM
    unsigned short* WtQKV = ws + 6 * PER_IN;
    unsigned short* WtO = WtQKV + (size_t)3 * DM * DM;
    unsigned short* Vtc = vb;  // vb dead after QKV GEMM
    unsigned short* ctx = qb;  // qb dead after QKV GEMM
    int* pos = (int*)d_out;    // dead until final GEMM overwrites d_out
    int* nk = pos + B_DIM * SEQ;

    // prep: 4608 cvt blocks + 2304 transpose blocks + 2 scan blocks
    prep<<<dim3(6914), 256, 0, stream>>>(q, k, v, qb, kb, vb,
                                         Wq, Wk, Wv, Wo, WtQKV, mask, pos, nk);

    gemm128<1, 128><<<dim3(MROWS / 128, 3 * DM / 128), 256, 0, stream>>>(
        qb, kb, vb, WtQKV, bq, bk, bv, pos, Qh, Kc, Vc);

    gatherV<<<dim3(SEQ / 64, B_DIM * H_), 256, 0, stream>>>(Vc, nk, Kc, Vtc);

    attn_fa<<<dim3(SEQ / 64, B_DIM * H_), 256, 0, stream>>>(Qh, Kc, Vtc, nk, ctx);

    gemm128<0, 64><<<dim3(MROWS / 64, DM / 128), 256, 0, stream>>>(
        ctx, ctx, ctx, WtO, bo, bo, bo, pos, d_out, d_out, d_out);
}